// Round 8
// baseline (570.491 us; speedup 1.0000x reference)
//
#include <hip/hip_runtime.h>
#include <cstdint>
#include <cstddef>

// ---------------------------------------------------------------------------
// Problem constants
// ---------------------------------------------------------------------------
#define NT      16384      // B*T tokens
#define DIM     768
#define TT      16         // tokens per block (halved -> 1024 blocks, 4/CU)
#define KA      64         // A-chunk (k per LDS stage)
#define NCA     (DIM/KA)   // 12 chunks
#define ALPHA_OFF 802816   // NT*49

// ws layout (floats)
#define WS_WCAT   0          // 768*512 = 393216 (+ overrun-read pad, harmless)
#define WS_GA     393216     // 128
#define WS_CBIAS  393344     // 128
#define WS_V1     393472     // 128
#define WS_V2     393600     // 128
#define WS_V3     393728     // 128
#define WS_CHEFF  393856     // 512 (transposed [k][m])
#define WS_C4     394368     // 4

__device__ __forceinline__ float silu_f(float x) { return x / (1.0f + expf(-x)); }

// ---------------------------------------------------------------------------
// Fused prep kernel, 97 blocks x 256 threads.  (UNCHANGED)
// Blocks 0..95: 64x64 tile transpose building wcat[k][pos], PERMUTED columns:
// orig col j (g=j>>3, r=j&7) -> pos = (r<4) ? g*4+r : 256+g*4+(r-4).
// Block 96: small precomputes (gA, cbias, v1..v3, cheff_t, c4).
// ---------------------------------------------------------------------------
__global__ void k_prep(const float* __restrict__ bw1, const float* __restrict__ mw1,
                       const float* __restrict__ g, const float* __restrict__ mb1,
                       const float* __restrict__ lnb, const float* __restrict__ pe,
                       const float* __restrict__ chw, const float* __restrict__ chb,
                       const float* __restrict__ phw, const float* __restrict__ phb,
                       const float* __restrict__ bil, const float* __restrict__ mob,
                       const int* __restrict__ pidxp, float* __restrict__ wcat,
                       float* __restrict__ gA, float* __restrict__ cbias,
                       float* __restrict__ v1, float* __restrict__ v2,
                       float* __restrict__ v3, float* __restrict__ cheff_t,
                       float* __restrict__ c4) {
    __shared__ float tilebuf[64][65];
    __shared__ float u[32];
    int tid = threadIdx.x;

    if (blockIdx.x == 96) {
        int pidx = *pidxp;
        if (tid < 32) u[tid] = pe[pidx * 32 + tid];
        __syncthreads();
        {
            int j = tid >> 1, half = tid & 1;
            const float* row = mw1 + (size_t)j * 1540 + half * 384;
            const float* gp = g + half * 384;
            const float* bp = lnb + half * 384;
            float sg_ = 0.f, sb_ = 0.f;
            for (int k = 0; k < 384; k += 4) {
                float4 rv = *(const float4*)(row + k);
                float4 gv = *(const float4*)(gp + k);
                float4 bv = *(const float4*)(bp + k);
                sg_ += rv.x * gv.x + rv.y * gv.y + rv.z * gv.z + rv.w * gv.w;
                sb_ += rv.x * bv.x + rv.y * bv.y + rv.z * bv.z + rv.w * bv.w;
            }
            sg_ += __shfl_xor(sg_, 1);
            sb_ += __shfl_xor(sb_, 1);
            if (half == 0) {
                const float* rowf = mw1 + (size_t)j * 1540;
                float pf = (float)pidx * (1.0f / 11.0f);
                gA[j] = sg_;
                v1[j] = rowf[1536];
                v2[j] = rowf[1537];
                v3[j] = rowf[1538];
                cbias[j] = sb_ + pf * rowf[1539] + mb1[j];
            }
        }
        for (int idx = tid; idx < 512; idx += 256) {
            int k = idx >> 2, m = idx & 3;
            float s = chw[m * 128 + k];
            for (int kk = 0; kk < 32; kk++) s += u[kk] * bil[(size_t)(m * 32 + kk) * 128 + k];
            cheff_t[k * 4 + m] = s;
        }
        if (tid < 4) {
            float s = chb[tid] + phb[tid] + mob[tid];
            for (int kk = 0; kk < 32; kk++) s += u[kk] * phw[tid * 32 + kk];
            c4[tid] = s;
        }
        return;
    }

    int jt = blockIdx.x & 7, kt = blockIdx.x >> 3;
    int j0 = jt * 64, k0 = kt * 64;

    {   // coalesced read: thread (jl, kc) reads 16 consecutive k of row j0+jl
        int jl = tid >> 2, kc = (tid & 3) * 16;
        int j = j0 + jl;
        const float* src;
        if (j0 < 256)      src = bw1 + (size_t)j * DIM + k0;
        else if (j0 < 384) src = mw1 + (size_t)(j - 256) * 1540 + k0;
        else               src = mw1 + (size_t)(j - 384) * 1540 + 768 + k0;
#pragma unroll
        for (int q = 0; q < 16; q += 4) {
            float4 v = *(const float4*)(src + kc + q);
            tilebuf[jl][kc + q + 0] = v.x;
            tilebuf[jl][kc + q + 1] = v.y;
            tilebuf[jl][kc + q + 2] = v.z;
            tilebuf[jl][kc + q + 3] = v.w;
        }
    }
    __syncthreads();
    {   // permuted write: thread (kl, jc) handles orig cols j0+jc .. j0+jc+15
        int kl = tid >> 2, jc = (tid & 3) * 16;
        int k = k0 + kl;
        float scale = (j0 >= 256 && j0 < 384) ? g[k] : 1.0f;
        int g0 = (j0 + jc) >> 3;  // even group index
        float* dstA = wcat + (size_t)k * 512 + g0 * 4;
        float* dstB = dstA + 256;
        float4 A1, A2, B1, B2;
        A1.x = tilebuf[jc + 0][kl] * scale;  A1.y = tilebuf[jc + 1][kl] * scale;
        A1.z = tilebuf[jc + 2][kl] * scale;  A1.w = tilebuf[jc + 3][kl] * scale;
        B1.x = tilebuf[jc + 4][kl] * scale;  B1.y = tilebuf[jc + 5][kl] * scale;
        B1.z = tilebuf[jc + 6][kl] * scale;  B1.w = tilebuf[jc + 7][kl] * scale;
        A2.x = tilebuf[jc + 8][kl] * scale;  A2.y = tilebuf[jc + 9][kl] * scale;
        A2.z = tilebuf[jc + 10][kl] * scale; A2.w = tilebuf[jc + 11][kl] * scale;
        B2.x = tilebuf[jc + 12][kl] * scale; B2.y = tilebuf[jc + 13][kl] * scale;
        B2.z = tilebuf[jc + 14][kl] * scale; B2.w = tilebuf[jc + 15][kl] * scale;
        *(float4*)(dstA) = A1;
        *(float4*)(dstA + 4) = A2;
        *(float4*)(dstB) = B1;
        *(float4*)(dstB + 4) = B2;
    }
}

// ---------------------------------------------------------------------------
// A-staging helpers (TT=16). Chunk = 64 k x 32 rows (16 h-tokens | 16 ex) in
// [k][row'] layout with swizzle row' = (row + 4*(k>>2)) & 31:
//   - global read: 16 lanes (kq=0..15) cover one 256B row segment -> coalesced
//   - ds_write_b32 x4: bank = (row+4kq)&31 -> 2 lanes/bank (free)
//   - compute ds_read_b128: all lanes of a wave read 1-2 broadcast addrs,
//     row' stays 4-aligned (shift multiple of 4) -> no wrap, conflict-free
// ---------------------------------------------------------------------------
__device__ __forceinline__ float4 stage_ld(const float* __restrict__ h,
                                           const float* __restrict__ ex,
                                           int tok0, int kb, int s) {
    int kq = s & 15, row = s >> 4;  // row 0..31
    const float* src = (row < 16) ? (h + (size_t)(tok0 + row) * DIM)
                                  : (ex + (size_t)(tok0 + row - 16) * DIM);
    return *(const float4*)(src + kb + kq * 4);
}
__device__ __forceinline__ void stage_st(float* buf, int s, float4 v) {
    int kq = s & 15, row = s >> 4;
    int rp = (row + 4 * kq) & 31;
    float* d = buf + kq * 128 + rp;   // word (4*kq+e)*32 + rp
    d[0] = v.x; d[32] = v.y; d[64] = v.z; d[96] = v.w;
}

// ---------------------------------------------------------------------------
// Main fused kernel. 1024 blocks x 256 threads, 16 tokens per block.
// 4 blocks/CU (31KB LDS, <=128 VGPR) -> 16 waves/CU = 4 waves/SIMD.
// W streamed from global (L2-resident wcat, depth-1 prefetch); A LDS-staged
// in double-buffered 64-k chunks. Thread (ng=tid&63, mg=tid>>6) owns tokens
// t0=4mg..+3 and orig cols 8ng..8ng+7 (permuted wcat slots 4ng, 256+4ng).
// Shared layout (floats), F[7713] = 30.9 KB:
//   [0,4096)    : union { abuf[2][2048] | a1[16][256] | cbuf[16][132] }
//   [4096,6144) : c1[16][128]
//   [6144,6928) : basebuf[16][49]
//   [6928,7056) : stats[16][8]
//   [7056,7568) : cheff_s[512]
//   [7568,7632) : alpha_s[16][4]
//   [7632,7636) : c4_s
//   [7636,7664) : msw_s[28]
//   [7664,7713) : sg_s[49] (ints)
// ---------------------------------------------------------------------------
__launch_bounds__(256, 4)
__global__ void k_main(const float* __restrict__ h, const float* __restrict__ ex,
                       const float* __restrict__ lam, const float* __restrict__ mup,
                       const float* __restrict__ bb1, const float* __restrict__ bw2,
                       const float* __restrict__ bb2, const float* __restrict__ mw2,
                       const float* __restrict__ mb2, const float* __restrict__ msw,
                       const int* __restrict__ sg, const float* __restrict__ wcat,
                       const float* __restrict__ gA, const float* __restrict__ cbias,
                       const float* __restrict__ v1w, const float* __restrict__ v2w,
                       const float* __restrict__ v3w, const float* __restrict__ cheff_t,
                       const float* __restrict__ c4, float* __restrict__ out) {
    __shared__ float F[7713];
    float* c1      = F + 4096;
    float* basebuf = F + 6144;
    float* stats   = F + 6928;
    float* cheff_s = F + 7056;
    float* alpha_s = F + 7568;
    float* c4_s    = F + 7632;
    float* msw_s   = F + 7636;
    int*   sg_s    = (int*)(F + 7664);

    const int tid = threadIdx.x;
    const int bid = blockIdx.x;
    const int tok0 = bid * TT;

    // --- small constant preloads ---
    if (tid < 49) sg_s[tid] = sg[tid];
    if (tid >= 64 && tid < 92) msw_s[tid - 64] = msw[tid - 64];
    if (tid >= 96 && tid < 100) c4_s[tid - 96] = c4[tid - 96];
    for (int i = tid; i < 512; i += 256) cheff_s[i] = cheff_t[i];

    // --- issue chunk-0 A staging loads early (latency hidden under stats) ---
    float4 s0 = stage_ld(h, ex, tok0, 0, tid);
    float4 s1 = stage_ld(h, ex, tok0, 0, tid + 256);

    // --- stats pass: 16 threads per token ---
    {
        int t = tid >> 4, r = tid & 15;
        const float* hp = h + (size_t)(tok0 + t) * DIM;
        const float* lp = lam + (size_t)(tok0 + t) * DIM;
        const float* mp = mup + (size_t)(tok0 + t) * DIM;
        float sh = 0.f, sh2 = 0.f, sll = 0.f, sll2 = 0.f, sd = 0.f;
        for (int i = 0; i < 12; i++) {
            int k0 = i * 64 + r * 4;
            float4 hv = *(const float4*)(hp + k0);
            float4 lv = *(const float4*)(lp + k0);
            float4 mv = *(const float4*)(mp + k0);
#pragma unroll
            for (int e = 0; e < 4; e++) {
                float hx = (&hv.x)[e];
                float lx = fmaxf((&lv.x)[e], 1e-6f);
                float mx = (&mv.x)[e];
                sh += hx; sh2 += hx * hx;
                float ll = logf(lx);
                sll += ll; sll2 += ll * ll;
                float dd = hx - mx; sd += dd * dd;
            }
        }
#pragma unroll
        for (int off = 1; off < 16; off <<= 1) {
            sh += __shfl_xor(sh, off);  sh2 += __shfl_xor(sh2, off);
            sll += __shfl_xor(sll, off); sll2 += __shfl_xor(sll2, off);
            sd += __shfl_xor(sd, off);
        }
        if (r == 0) {
            float m = sh * (1.f / 768.f);
            float var = sh2 * (1.f / 768.f) - m * m;
            float istd = rsqrtf(var + 1e-5f);
            float mll = sll * (1.f / 768.f);
            float vll = (sll2 - 768.f * mll * mll) * (1.f / 767.f);
            float sstd = fmaxf(sqrtf(fmaxf(vll, 0.f)), 1e-6f);
            float dmu = sqrtf(sd * (1.f / 768.f) + 1e-8f);
            float* st = stats + t * 8;
            st[0] = m; st[1] = istd; st[2] = mll; st[3] = sstd; st[4] = dmu;
        }
    }

    // --- write chunk-0 A into buffer 0 ---
    stage_st(F, tid, s0);
    stage_st(F, tid + 256, s1);
    __syncthreads();

    // --- main GEMM: [16 tok] x [512 outs], K=768 ---
    const int ng = tid & 63, mg = tid >> 6;
    const int j0 = ng * 8, t0 = mg * 4;
    const int arow = t0 + ((ng < 48) ? 0 : 16);  // h rows [0,16), ex rows [16,32)

    float acc[4][8] = {};

    int cur = 0;
    for (int c = 0; c < NCA; c++) {
        const int kb = c * KA;
        const bool more = (c + 1 < NCA);
        const float* ab = F + cur * 2048;
        float* nb = F + (cur ^ 1) * 2048;
        const float* wb0 = wcat + (size_t)kb * 512 + ng * 4;

        if (more) {  // next chunk's A (consumed at chunk end: ~full chunk of cover)
            s0 = stage_ld(h, ex, tok0, kb + KA, tid);
            s1 = stage_ld(h, ex, tok0, kb + KA, tid + 256);
        }

        float4 wl = *(const float4*)(wb0);
        float4 wh = *(const float4*)(wb0 + 256);

#pragma unroll 4
        for (int kk = 0; kk < KA; kk++) {
            // depth-1 W prefetch (final iter of last chunk reads row 768: in-ws pad)
            const float* wn = wb0 + (size_t)(kk + 1) * 512;
            float4 wln = *(const float4*)(wn);
            float4 whn = *(const float4*)(wn + 256);
            int rp = (arow + 4 * (kk >> 2)) & 31;
            float4 a0 = *(const float4*)(ab + kk * 32 + rp);
            float av[4] = {a0.x, a0.y, a0.z, a0.w};
            float wv[8] = {wl.x, wl.y, wl.z, wl.w, wh.x, wh.y, wh.z, wh.w};
#pragma unroll
            for (int i = 0; i < 4; i++)
#pragma unroll
                for (int j = 0; j < 8; j++)
                    acc[i][j] = fmaf(av[i], wv[j], acc[i][j]);
            wl = wln; wh = whn;
        }
        if (more) {
            stage_st(nb, tid, s0);
            stage_st(nb, tid + 256, s1);
        }
        __syncthreads();
        cur ^= 1;
    }

    // --- epilogue part 1: a1 = silu(acc+b1) [ng<32]; c1 P-side [ng in 32..47] ---
    float* a1 = F;  // staging region dead
    if (ng < 32) {
        float4 ba = *(const float4*)(bb1 + j0);
        float4 bb = *(const float4*)(bb1 + j0 + 4);
#pragma unroll
        for (int i = 0; i < 4; i++) {
            float4 v0, v1;
            v0.x = silu_f(acc[i][0] + ba.x);
            v0.y = silu_f(acc[i][1] + ba.y);
            v0.z = silu_f(acc[i][2] + ba.z);
            v0.w = silu_f(acc[i][3] + ba.w);
            v1.x = silu_f(acc[i][4] + bb.x);
            v1.y = silu_f(acc[i][5] + bb.y);
            v1.z = silu_f(acc[i][6] + bb.z);
            v1.w = silu_f(acc[i][7] + bb.w);
            *(float4*)(a1 + (t0 + i) * 256 + j0) = v0;
            *(float4*)(a1 + (t0 + i) * 256 + j0 + 4) = v1;
        }
    } else if (ng < 48) {
        int jj0 = j0 - 256;  // in [0,128), step 8
        float4 ga0 = *(const float4*)(gA + jj0),    ga1 = *(const float4*)(gA + jj0 + 4);
        float4 cb0 = *(const float4*)(cbias + jj0), cb1 = *(const float4*)(cbias + jj0 + 4);
        float4 w10 = *(const float4*)(v1w + jj0),   w11 = *(const float4*)(v1w + jj0 + 4);
        float4 w20 = *(const float4*)(v2w + jj0),   w21 = *(const float4*)(v2w + jj0 + 4);
        float4 w30 = *(const float4*)(v3w + jj0),   w31 = *(const float4*)(v3w + jj0 + 4);
#pragma unroll
        for (int i = 0; i < 4; i++) {
            const float* st = stats + (t0 + i) * 8;
            float m = st[0], istd = st[1], mll = st[2], sll = st[3], dmu = st[4];
            float nim = -istd * m;
            float4 r0, r1;
            r0.x = istd * acc[i][0] + nim * ga0.x + mll * w10.x + sll * w20.x + dmu * w30.x + cb0.x;
            r0.y = istd * acc[i][1] + nim * ga0.y + mll * w10.y + sll * w20.y + dmu * w30.y + cb0.y;
            r0.z = istd * acc[i][2] + nim * ga0.z + mll * w10.z + sll * w20.z + dmu * w30.z + cb0.z;
            r0.w = istd * acc[i][3] + nim * ga0.w + mll * w10.w + sll * w20.w + dmu * w30.w + cb0.w;
            r1.x = istd * acc[i][4] + nim * ga1.x + mll * w11.x + sll * w21.x + dmu * w31.x + cb1.x;
            r1.y = istd * acc[i][5] + nim * ga1.y + mll * w11.y + sll * w21.y + dmu * w31.y + cb1.y;
            r1.z = istd * acc[i][6] + nim * ga1.z + mll * w11.z + sll * w21.z + dmu * w31.z + cb1.z;
            r1.w = istd * acc[i][7] + nim * ga1.w + mll * w11.w + sll * w21.w + dmu * w31.w + cb1.w;
            *(float4*)(c1 + (t0 + i) * 128 + jj0) = r0;
            *(float4*)(c1 + (t0 + i) * 128 + jj0 + 4) = r1;
        }
    }
    __syncthreads();
    // Q-side add + silu (ng >= 48)
    if (ng >= 48) {
        int jj0 = j0 - 384;  // in [0,128), step 8
#pragma unroll
        for (int i = 0; i < 4; i++) {
            float* cp = c1 + (t0 + i) * 128 + jj0;
            float4 c0 = *(const float4*)cp;
            float4 cv1 = *(const float4*)(cp + 4);
            c0.x = silu_f(c0.x + acc[i][0]);
            c0.y = silu_f(c0.y + acc[i][1]);
            c0.z = silu_f(c0.z + acc[i][2]);
            c0.w = silu_f(c0.w + acc[i][3]);
            cv1.x = silu_f(cv1.x + acc[i][4]);
            cv1.y = silu_f(cv1.y + acc[i][5]);
            cv1.z = silu_f(cv1.z + acc[i][6]);
            cv1.w = silu_f(cv1.w + acc[i][7]);
            *(float4*)cp = c0;
            *(float4*)(cp + 4) = cv1;
        }
    }
    __syncthreads();

    // --- GEMM1b: base = a1 @ base_w2^T + b2  (16x49, K=256) ---
    for (int o = tid; o < TT * 49; o += 256) {
        int t = o / 49, s = o - t * 49;
        const float* ar = a1 + t * 256;
        const float* wr = bw2 + s * 256;
        float accv = bb2[s];
        for (int k = 0; k < 256; k += 4) {
            float4 av = *(const float4*)(ar + k);
            float4 wv = *(const float4*)(wr + k);
            accv += av.x * wv.x + av.y * wv.y + av.z * wv.z + av.w * wv.w;
        }
        basebuf[o] = accv;
    }
    __syncthreads();

    // --- GEMM2b: c = c1 @ mlp_w2^T + b2  (16x128, K=128) -> cbuf (overlays a1) ---
    float* cbuf = F;  // stride 132
    {
        int j = tid & 127, tg = tid >> 7;
        float accv[8];
#pragma unroll
        for (int tt = 0; tt < 8; tt++) accv[tt] = 0.f;
        const float* wr = mw2 + (size_t)j * 128;
        const float* cr = c1 + tg * 8 * 128;
        for (int k = 0; k < 128; k += 4) {
            float4 wv = *(const float4*)(wr + k);
#pragma unroll
            for (int tt = 0; tt < 8; tt++) {
                float4 cv = *(const float4*)(cr + tt * 128 + k);
                accv[tt] += cv.x * wv.x + cv.y * wv.y + cv.z * wv.z + cv.w * wv.w;
            }
        }
        float b = mb2[j];
        __syncthreads();  // ensure all a1 reads (GEMM1b) done before overlay write
#pragma unroll
        for (int tt = 0; tt < 8; tt++) cbuf[(tg * 8 + tt) * 132 + j] = accv[tt] + b;
    }
    __syncthreads();

    // --- mode logits + softmax(4) -> alpha; write alpha to out ---
    if (tid < 64) {
        int t = tid >> 2, m = tid & 3;
        const float* cr = cbuf + t * 132;
        float e = c4_s[m];
        for (int k = 0; k < 128; k++) e += cr[k] * cheff_s[k * 4 + m];
        float mx = fmaxf(e, __shfl_xor(e, 1));
        mx = fmaxf(mx, __shfl_xor(mx, 2));
        float ev = expf(e - mx);
        float sum = ev + __shfl_xor(ev, 1);
        sum += __shfl_xor(sum, 2);
        float al = ev / sum;
        alpha_s[t * 4 + m] = al;
        out[ALPHA_OFF + (size_t)(tok0 + t) * 4 + m] = al;
    }
    __syncthreads();

    // --- K: masked stage-graph softmax over rows of 7 ---
    if (tid < TT * 7) {
        int t = tid / 7, i = tid - t * 7;
        const float* al = alpha_s + t * 4;
        float sb[7];
#pragma unroll
        for (int s = 0; s < 7; s++)
            sb[s] = al[0] * msw_s[s * 4 + 0] + al[1] * msw_s[s * 4 + 1] +
                    al[2] * msw_s[s * 4 + 2] + al[3] * msw_s[s * 4 + 3];
        const float* br = basebuf + t * 49 + i * 7;
        const int* mrow = sg_s + i * 7;
        float vals[7];
        float mx = -1e30f;
#pragma unroll
        for (int j = 0; j < 7; j++) {
            float vv = br[j] + sb[j];
            vals[j] = mrow[j] ? vv : -1e30f;
            mx = fmaxf(mx, vals[j]);
        }
        float e[7], sum = 0.f;
#pragma unroll
        for (int j = 0; j < 7; j++) {
            e[j] = mrow[j] ? expf(vals[j] - mx) : 0.f;
            sum += e[j];
        }
        float inv = 1.f / sum;
        size_t off = (size_t)(tok0 + t) * 49 + i * 7;
#pragma unroll
        for (int j = 0; j < 7; j++) out[off + j] = e[j] * inv;
    }
}

// ---------------------------------------------------------------------------
extern "C" void kernel_launch(void* const* d_in, const int* in_sizes, int n_in,
                              void* d_out, int out_size, void* d_ws, size_t ws_size,
                              hipStream_t stream) {
    const float* h    = (const float*)d_in[0];
    const float* ex   = (const float*)d_in[1];
    const float* lam  = (const float*)d_in[2];
    const float* mup  = (const float*)d_in[3];
    const float* bw1  = (const float*)d_in[4];
    const float* bb1  = (const float*)d_in[5];
    const float* bw2  = (const float*)d_in[6];
    const float* bb2  = (const float*)d_in[7];
    const float* lng  = (const float*)d_in[8];
    const float* lnb  = (const float*)d_in[9];
    const float* mw1  = (const float*)d_in[10];
    const float* mb1  = (const float*)d_in[11];
    const float* mw2  = (const float*)d_in[12];
    const float* mb2  = (const float*)d_in[13];
    const float* pe   = (const float*)d_in[14];
    const float* chw  = (const float*)d_in[15];
    const float* chb  = (const float*)d_in[16];
    const float* phw  = (const float*)d_in[17];
    const float* phb  = (const float*)d_in[18];
    const float* bil  = (const float*)d_in[19];
    const float* mob  = (const float*)d_in[20];
    const float* msw  = (const float*)d_in[21];
    const int*   sg   = (const int*)d_in[22];
    const int*   pidx = (const int*)d_in[23];
    float* out = (float*)d_out;
    float* ws = (float*)d_ws;

    float* wcat  = ws + WS_WCAT;
    float* gA    = ws + WS_GA;
    float* cbias = ws + WS_CBIAS;
    float* v1    = ws + WS_V1;
    float* v2    = ws + WS_V2;
    float* v3    = ws + WS_V3;
    float* cheff = ws + WS_CHEFF;
    float* c4    = ws + WS_C4;

    hipLaunchKernelGGL(k_prep, dim3(97), dim3(256), 0, stream, bw1, mw1, lng, mb1, lnb, pe,
                       chw, chb, phw, phb, bil, mob, pidx, wcat, gA, cbias, v1, v2, v3,
                       cheff, c4);
    hipLaunchKernelGGL(k_main, dim3(NT / TT), dim3(256), 0, stream, h, ex, lam, mup, bb1, bw2,
                       bb2, mw2, mb2, msw, sg, wcat, gA, cbias, v1, v2, v3, cheff, c4, out);
}

// Round 9
// 499.980 us; speedup vs baseline: 1.1410x; 1.1410x over previous
//
#include <hip/hip_runtime.h>
#include <cstdint>
#include <cstddef>

// ---------------------------------------------------------------------------
// Problem constants
// ---------------------------------------------------------------------------
#define NT      16384      // B*T tokens
#define DIM     768
#define TT      16         // tokens per block -> 1024 blocks, 4/CU
#define KA      64         // A-chunk (k per LDS stage)
#define NCA     (DIM/KA)   // 12 chunks
#define ALPHA_OFF 802816   // NT*49

// ws layout (floats)
#define WS_WCAT   0          // 768*512 = 393216 (+ overrun-read pad, harmless)
#define WS_GA     393216     // 128
#define WS_CBIAS  393344     // 128
#define WS_V1     393472     // 128
#define WS_V2     393600     // 128
#define WS_V3     393728     // 128
#define WS_CHEFF  393856     // 512 (transposed [k][m])
#define WS_C4     394368     // 4

__device__ __forceinline__ float silu_f(float x) { return x / (1.0f + expf(-x)); }

// ---------------------------------------------------------------------------
// Fused prep kernel, 97 blocks x 256 threads.
// Blocks 0..95: 64x64 tile STRAIGHT transpose building wcat[k][j], k<768:
//   j <  256 : base_w1[j][k]
//   j <  384 : mlp_w1[j-256][k] * ln_g[k]     (LN-scale folded in)
//   else     : mlp_w1[j-384][768+k]
// (No column permutation: k_main waves read contiguous 512B col-quarters.)
// Block 96: small precomputes (gA, cbias, v1..v3, cheff_t, c4).
// ---------------------------------------------------------------------------
__global__ void k_prep(const float* __restrict__ bw1, const float* __restrict__ mw1,
                       const float* __restrict__ g, const float* __restrict__ mb1,
                       const float* __restrict__ lnb, const float* __restrict__ pe,
                       const float* __restrict__ chw, const float* __restrict__ chb,
                       const float* __restrict__ phw, const float* __restrict__ phb,
                       const float* __restrict__ bil, const float* __restrict__ mob,
                       const int* __restrict__ pidxp, float* __restrict__ wcat,
                       float* __restrict__ gA, float* __restrict__ cbias,
                       float* __restrict__ v1, float* __restrict__ v2,
                       float* __restrict__ v3, float* __restrict__ cheff_t,
                       float* __restrict__ c4) {
    __shared__ float tilebuf[64][65];
    __shared__ float u[32];
    int tid = threadIdx.x;

    if (blockIdx.x == 96) {
        int pidx = *pidxp;
        if (tid < 32) u[tid] = pe[pidx * 32 + tid];
        __syncthreads();
        {
            int j = tid >> 1, half = tid & 1;
            const float* row = mw1 + (size_t)j * 1540 + half * 384;
            const float* gp = g + half * 384;
            const float* bp = lnb + half * 384;
            float sg_ = 0.f, sb_ = 0.f;
            for (int k = 0; k < 384; k += 4) {
                float4 rv = *(const float4*)(row + k);
                float4 gv = *(const float4*)(gp + k);
                float4 bv = *(const float4*)(bp + k);
                sg_ += rv.x * gv.x + rv.y * gv.y + rv.z * gv.z + rv.w * gv.w;
                sb_ += rv.x * bv.x + rv.y * bv.y + rv.z * bv.z + rv.w * bv.w;
            }
            sg_ += __shfl_xor(sg_, 1);
            sb_ += __shfl_xor(sb_, 1);
            if (half == 0) {
                const float* rowf = mw1 + (size_t)j * 1540;
                float pf = (float)pidx * (1.0f / 11.0f);
                gA[j] = sg_;
                v1[j] = rowf[1536];
                v2[j] = rowf[1537];
                v3[j] = rowf[1538];
                cbias[j] = sb_ + pf * rowf[1539] + mb1[j];
            }
        }
        for (int idx = tid; idx < 512; idx += 256) {
            int k = idx >> 2, m = idx & 3;
            float s = chw[m * 128 + k];
            for (int kk = 0; kk < 32; kk++) s += u[kk] * bil[(size_t)(m * 32 + kk) * 128 + k];
            cheff_t[k * 4 + m] = s;
        }
        if (tid < 4) {
            float s = chb[tid] + phb[tid] + mob[tid];
            for (int kk = 0; kk < 32; kk++) s += u[kk] * phw[tid * 32 + kk];
            c4[tid] = s;
        }
        return;
    }

    int jt = blockIdx.x & 7, kt = blockIdx.x >> 3;
    int j0 = jt * 64, k0 = kt * 64;

    {   // coalesced read: thread (jl, kc) reads 16 consecutive k of row j0+jl
        int jl = tid >> 2, kc = (tid & 3) * 16;
        int j = j0 + jl;
        const float* src;
        if (j0 < 256)      src = bw1 + (size_t)j * DIM + k0;
        else if (j0 < 384) src = mw1 + (size_t)(j - 256) * 1540 + k0;
        else               src = mw1 + (size_t)(j - 384) * 1540 + 768 + k0;
#pragma unroll
        for (int q = 0; q < 16; q += 4) {
            float4 v = *(const float4*)(src + kc + q);
            tilebuf[jl][kc + q + 0] = v.x;
            tilebuf[jl][kc + q + 1] = v.y;
            tilebuf[jl][kc + q + 2] = v.z;
            tilebuf[jl][kc + q + 3] = v.w;
        }
    }
    __syncthreads();
    {   // coalesced write: thread (kl, jc) writes 16 consecutive j of row k0+kl
        int kl = tid >> 2, jc = (tid & 3) * 16;
        int k = k0 + kl;
        float scale = (j0 >= 256 && j0 < 384) ? g[k] : 1.0f;
        float* dst = wcat + (size_t)k * 512 + j0 + jc;
#pragma unroll
        for (int q = 0; q < 16; q += 4) {
            float4 v;
            v.x = tilebuf[jc + q + 0][kl] * scale;
            v.y = tilebuf[jc + q + 1][kl] * scale;
            v.z = tilebuf[jc + q + 2][kl] * scale;
            v.w = tilebuf[jc + q + 3][kl] * scale;
            *(float4*)(dst + q) = v;
        }
    }
}

// ---------------------------------------------------------------------------
// A-staging helpers (TT=16). Chunk = 64 k x 32 rows (16 h-tokens | 16 ex) in
// [k][row'] layout with swizzle row' = (row + 4*(k>>2)) & 31:
//   - global read: 16 lanes (kq=0..15) cover one 256B row segment -> coalesced
//   - ds_write_b32 x4: bank = (row+4kq)&31 -> 2 lanes/bank (free)
//   - compute ds_read_b128: broadcast addrs, 4-aligned, conflict-free
// ---------------------------------------------------------------------------
__device__ __forceinline__ float4 stage_ld(const float* __restrict__ h,
                                           const float* __restrict__ ex,
                                           int tok0, int kb, int s) {
    int kq = s & 15, row = s >> 4;  // row 0..31
    const float* src = (row < 16) ? (h + (size_t)(tok0 + row) * DIM)
                                  : (ex + (size_t)(tok0 + row - 16) * DIM);
    return *(const float4*)(src + kb + kq * 4);
}
__device__ __forceinline__ void stage_st(float* buf, int s, float4 v) {
    int kq = s & 15, row = s >> 4;
    int rp = (row + 4 * kq) & 31;
    float* d = buf + kq * 128 + rp;   // word (4*kq+e)*32 + rp
    d[0] = v.x; d[32] = v.y; d[64] = v.z; d[96] = v.w;
}

// ---------------------------------------------------------------------------
// Main fused kernel. 1024 blocks x 256 threads, 16 tokens per block.
// WAVE-COLUMN-SPLIT: wave w owns cols 128w..128w+127 for ALL 16 tokens;
// lane l: cols j0 = 128w + 4(l&31), tokens t0 = 8*(l>>5) .. +7.
//   -> W read per wave per k-step = ONE float4, uniform across half-waves
//      (512B/wave); the 4 waves together read each W row exactly once:
//      1.5MB L2 traffic per block, INDEPENDENT of occupancy.
//   -> A ds_read: 32 lanes broadcast same addr, conflict-free.
// W streamed from global with depth-1 prefetch; A LDS-staged (dbuf, 12
// barriers). 31KB LDS, acc[8][4] -> 4 blocks/CU = 4 waves/SIMD.
// Shared layout (floats), F[7713] = 30.9 KB:
//   [0,4096)    : union { abuf[2][2048] | a1[16][256] | cbuf[16][132] }
//   [4096,6144) : c1[16][128]
//   [6144,6928) : basebuf[16][49]
//   [6928,7056) : stats[16][8]
//   [7056,7568) : cheff_s[512]
//   [7568,7632) : alpha_s[16][4]
//   [7632,7636) : c4_s
//   [7636,7664) : msw_s[28]
//   [7664,7713) : sg_s[49] (ints)
// ---------------------------------------------------------------------------
__launch_bounds__(256, 4)
__global__ void k_main(const float* __restrict__ h, const float* __restrict__ ex,
                       const float* __restrict__ lam, const float* __restrict__ mup,
                       const float* __restrict__ bb1, const float* __restrict__ bw2,
                       const float* __restrict__ bb2, const float* __restrict__ mw2,
                       const float* __restrict__ mb2, const float* __restrict__ msw,
                       const int* __restrict__ sg, const float* __restrict__ wcat,
                       const float* __restrict__ gA, const float* __restrict__ cbias,
                       const float* __restrict__ v1w, const float* __restrict__ v2w,
                       const float* __restrict__ v3w, const float* __restrict__ cheff_t,
                       const float* __restrict__ c4, float* __restrict__ out) {
    __shared__ float F[7713];
    float* c1      = F + 4096;
    float* basebuf = F + 6144;
    float* stats   = F + 6928;
    float* cheff_s = F + 7056;
    float* alpha_s = F + 7568;
    float* c4_s    = F + 7632;
    float* msw_s   = F + 7636;
    int*   sg_s    = (int*)(F + 7664);

    const int tid = threadIdx.x;
    const int bid = blockIdx.x;
    const int tok0 = bid * TT;

    // --- small constant preloads ---
    if (tid < 49) sg_s[tid] = sg[tid];
    if (tid >= 64 && tid < 92) msw_s[tid - 64] = msw[tid - 64];
    if (tid >= 96 && tid < 100) c4_s[tid - 96] = c4[tid - 96];
    for (int i = tid; i < 512; i += 256) cheff_s[i] = cheff_t[i];

    // --- issue chunk-0 A staging loads early (latency hidden under stats) ---
    float4 s0 = stage_ld(h, ex, tok0, 0, tid);
    float4 s1 = stage_ld(h, ex, tok0, 0, tid + 256);

    // --- stats pass: 16 threads per token ---
    {
        int t = tid >> 4, r = tid & 15;
        const float* hp = h + (size_t)(tok0 + t) * DIM;
        const float* lp = lam + (size_t)(tok0 + t) * DIM;
        const float* mp = mup + (size_t)(tok0 + t) * DIM;
        float sh = 0.f, sh2 = 0.f, sll = 0.f, sll2 = 0.f, sd = 0.f;
        for (int i = 0; i < 12; i++) {
            int k0 = i * 64 + r * 4;
            float4 hv = *(const float4*)(hp + k0);
            float4 lv = *(const float4*)(lp + k0);
            float4 mv = *(const float4*)(mp + k0);
#pragma unroll
            for (int e = 0; e < 4; e++) {
                float hx = (&hv.x)[e];
                float lx = fmaxf((&lv.x)[e], 1e-6f);
                float mx = (&mv.x)[e];
                sh += hx; sh2 += hx * hx;
                float ll = logf(lx);
                sll += ll; sll2 += ll * ll;
                float dd = hx - mx; sd += dd * dd;
            }
        }
#pragma unroll
        for (int off = 1; off < 16; off <<= 1) {
            sh += __shfl_xor(sh, off);  sh2 += __shfl_xor(sh2, off);
            sll += __shfl_xor(sll, off); sll2 += __shfl_xor(sll2, off);
            sd += __shfl_xor(sd, off);
        }
        if (r == 0) {
            float m = sh * (1.f / 768.f);
            float var = sh2 * (1.f / 768.f) - m * m;
            float istd = rsqrtf(var + 1e-5f);
            float mll = sll * (1.f / 768.f);
            float vll = (sll2 - 768.f * mll * mll) * (1.f / 767.f);
            float sstd = fmaxf(sqrtf(fmaxf(vll, 0.f)), 1e-6f);
            float dmu = sqrtf(sd * (1.f / 768.f) + 1e-8f);
            float* st = stats + t * 8;
            st[0] = m; st[1] = istd; st[2] = mll; st[3] = sstd; st[4] = dmu;
        }
    }

    // --- write chunk-0 A into buffer 0 ---
    stage_st(F, tid, s0);
    stage_st(F, tid + 256, s1);
    __syncthreads();

    // --- main GEMM: [16 tok] x [512 outs], K=768, wave-column-split ---
    const int w = tid >> 6, l = tid & 63;
    const int j0 = w * 128 + (l & 31) * 4;        // this thread's 4 cols
    const int t0 = (l >> 5) * 8;                  // 8 tokens
    const int arow = t0 + ((w == 3) ? 16 : 0);    // h rows [0,16), ex rows [16,32)

    float acc[8][4] = {};

    int cur = 0;
    for (int c = 0; c < NCA; c++) {
        const int kb = c * KA;
        const bool more = (c + 1 < NCA);
        const float* ab = F + cur * 2048;
        float* nb = F + (cur ^ 1) * 2048;
        const float* wb0 = wcat + (size_t)kb * 512 + j0;

        if (more) {  // next chunk's A (consumed at chunk end: ~full chunk of cover)
            s0 = stage_ld(h, ex, tok0, kb + KA, tid);
            s1 = stage_ld(h, ex, tok0, kb + KA, tid + 256);
        }

        float4 wv4 = *(const float4*)(wb0);

#pragma unroll 4
        for (int kk = 0; kk < KA; kk++) {
            // depth-1 W prefetch (final iter of last chunk reads row 768: in-ws pad)
            float4 wn4 = *(const float4*)(wb0 + (size_t)(kk + 1) * 512);
            int rp = (arow + 4 * (kk >> 2)) & 31;
            float4 a0  = *(const float4*)(ab + kk * 32 + rp);
            float4 a1v = *(const float4*)(ab + kk * 32 + ((rp + 4) & 31));
            float av[8] = {a0.x, a0.y, a0.z, a0.w, a1v.x, a1v.y, a1v.z, a1v.w};
            float wv[4] = {wv4.x, wv4.y, wv4.z, wv4.w};
#pragma unroll
            for (int i = 0; i < 8; i++)
#pragma unroll
                for (int j = 0; j < 4; j++)
                    acc[i][j] = fmaf(av[i], wv[j], acc[i][j]);
            wv4 = wn4;
        }
        if (more) {
            stage_st(nb, tid, s0);
            stage_st(nb, tid + 256, s1);
        }
        __syncthreads();
        cur ^= 1;
    }

    // --- epilogue: a1 = silu(acc+b1) [w<2]; c1 P-side [w==2]; Q-side [w==3] ---
    float* a1 = F;  // staging region dead
    if (w < 2) {
        float4 ba = *(const float4*)(bb1 + j0);
#pragma unroll
        for (int i = 0; i < 8; i++) {
            float4 v0;
            v0.x = silu_f(acc[i][0] + ba.x);
            v0.y = silu_f(acc[i][1] + ba.y);
            v0.z = silu_f(acc[i][2] + ba.z);
            v0.w = silu_f(acc[i][3] + ba.w);
            *(float4*)(a1 + (t0 + i) * 256 + j0) = v0;
        }
    } else if (w == 2) {
        int jj0 = j0 - 256;  // in [0,128)
        float4 ga0 = *(const float4*)(gA + jj0);
        float4 cb0 = *(const float4*)(cbias + jj0);
        float4 w10 = *(const float4*)(v1w + jj0);
        float4 w20 = *(const float4*)(v2w + jj0);
        float4 w30 = *(const float4*)(v3w + jj0);
#pragma unroll
        for (int i = 0; i < 8; i++) {
            const float* st = stats + (t0 + i) * 8;
            float m = st[0], istd = st[1], mll = st[2], sll = st[3], dmu = st[4];
            float nim = -istd * m;
            float4 r0;
            r0.x = istd * acc[i][0] + nim * ga0.x + mll * w10.x + sll * w20.x + dmu * w30.x + cb0.x;
            r0.y = istd * acc[i][1] + nim * ga0.y + mll * w10.y + sll * w20.y + dmu * w30.y + cb0.y;
            r0.z = istd * acc[i][2] + nim * ga0.z + mll * w10.z + sll * w20.z + dmu * w30.z + cb0.z;
            r0.w = istd * acc[i][3] + nim * ga0.w + mll * w10.w + sll * w20.w + dmu * w30.w + cb0.w;
            *(float4*)(c1 + (t0 + i) * 128 + jj0) = r0;
        }
    }
    __syncthreads();
    // Q-side add + silu (wave 3)
    if (w == 3) {
        int jj0 = j0 - 384;  // in [0,128)
#pragma unroll
        for (int i = 0; i < 8; i++) {
            float* cp = c1 + (t0 + i) * 128 + jj0;
            float4 c0 = *(const float4*)cp;
            c0.x = silu_f(c0.x + acc[i][0]);
            c0.y = silu_f(c0.y + acc[i][1]);
            c0.z = silu_f(c0.z + acc[i][2]);
            c0.w = silu_f(c0.w + acc[i][3]);
            *(float4*)cp = c0;
        }
    }
    __syncthreads();

    // --- GEMM1b: base = a1 @ base_w2^T + b2  (16x49, K=256) ---
    for (int o = tid; o < TT * 49; o += 256) {
        int t = o / 49, s = o - t * 49;
        const float* ar = a1 + t * 256;
        const float* wr = bw2 + s * 256;
        float accv = bb2[s];
        for (int k = 0; k < 256; k += 4) {
            float4 av = *(const float4*)(ar + k);
            float4 wv = *(const float4*)(wr + k);
            accv += av.x * wv.x + av.y * wv.y + av.z * wv.z + av.w * wv.w;
        }
        basebuf[o] = accv;
    }
    __syncthreads();

    // --- GEMM2b: c = c1 @ mlp_w2^T + b2  (16x128, K=128) -> cbuf (overlays a1) ---
    float* cbuf = F;  // stride 132
    {
        int j = tid & 127, tg = tid >> 7;
        float accv[8];
#pragma unroll
        for (int tt = 0; tt < 8; tt++) accv[tt] = 0.f;
        const float* wr = mw2 + (size_t)j * 128;
        const float* cr = c1 + tg * 8 * 128;
        for (int k = 0; k < 128; k += 4) {
            float4 wv = *(const float4*)(wr + k);
#pragma unroll
            for (int tt = 0; tt < 8; tt++) {
                float4 cv = *(const float4*)(cr + tt * 128 + k);
                accv[tt] += cv.x * wv.x + cv.y * wv.y + cv.z * wv.z + cv.w * wv.w;
            }
        }
        float b = mb2[j];
        __syncthreads();  // ensure all a1 reads (GEMM1b) done before overlay write
#pragma unroll
        for (int tt = 0; tt < 8; tt++) cbuf[(tg * 8 + tt) * 132 + j] = accv[tt] + b;
    }
    __syncthreads();

    // --- mode logits + softmax(4) -> alpha; write alpha to out ---
    if (tid < 64) {
        int t = tid >> 2, m = tid & 3;
        const float* cr = cbuf + t * 132;
        float e = c4_s[m];
        for (int k = 0; k < 128; k++) e += cr[k] * cheff_s[k * 4 + m];
        float mx = fmaxf(e, __shfl_xor(e, 1));
        mx = fmaxf(mx, __shfl_xor(mx, 2));
        float ev = expf(e - mx);
        float sum = ev + __shfl_xor(ev, 1);
        sum += __shfl_xor(sum, 2);
        float al = ev / sum;
        alpha_s[t * 4 + m] = al;
        out[ALPHA_OFF + (size_t)(tok0 + t) * 4 + m] = al;
    }
    __syncthreads();

    // --- K: masked stage-graph softmax over rows of 7 ---
    if (tid < TT * 7) {
        int t = tid / 7, i = tid - t * 7;
        const float* al = alpha_s + t * 4;
        float sb[7];
#pragma unroll
        for (int s = 0; s < 7; s++)
            sb[s] = al[0] * msw_s[s * 4 + 0] + al[1] * msw_s[s * 4 + 1] +
                    al[2] * msw_s[s * 4 + 2] + al[3] * msw_s[s * 4 + 3];
        const float* br = basebuf + t * 49 + i * 7;
        const int* mrow = sg_s + i * 7;
        float vals[7];
        float mx = -1e30f;
#pragma unroll
        for (int j = 0; j < 7; j++) {
            float vv = br[j] + sb[j];
            vals[j] = mrow[j] ? vv : -1e30f;
            mx = fmaxf(mx, vals[j]);
        }
        float e[7], sum = 0.f;
#pragma unroll
        for (int j = 0; j < 7; j++) {
            e[j] = mrow[j] ? expf(vals[j] - mx) : 0.f;
            sum += e[j];
        }
        float inv = 1.f / sum;
        size_t off = (size_t)(tok0 + t) * 49 + i * 7;
#pragma unroll
        for (int j = 0; j < 7; j++) out[off + j] = e[j] * inv;
    }
}

// ---------------------------------------------------------------------------
extern "C" void kernel_launch(void* const* d_in, const int* in_sizes, int n_in,
                              void* d_out, int out_size, void* d_ws, size_t ws_size,
                              hipStream_t stream) {
    const float* h    = (const float*)d_in[0];
    const float* ex   = (const float*)d_in[1];
    const float* lam  = (const float*)d_in[2];
    const float* mup  = (const float*)d_in[3];
    const float* bw1  = (const float*)d_in[4];
    const float* bb1  = (const float*)d_in[5];
    const float* bw2  = (const float*)d_in[6];
    const float* bb2  = (const float*)d_in[7];
    const float* lng  = (const float*)d_in[8];
    const float* lnb  = (const float*)d_in[9];
    const float* mw1  = (const float*)d_in[10];
    const float* mb1  = (const float*)d_in[11];
    const float* mw2  = (const float*)d_in[12];
    const float* mb2  = (const float*)d_in[13];
    const float* pe   = (const float*)d_in[14];
    const float* chw  = (const float*)d_in[15];
    const float* chb  = (const float*)d_in[16];
    const float* phw  = (const float*)d_in[17];
    const float* phb  = (const float*)d_in[18];
    const float* bil  = (const float*)d_in[19];
    const float* mob  = (const float*)d_in[20];
    const float* msw  = (const float*)d_in[21];
    const int*   sg   = (const int*)d_in[22];
    const int*   pidx = (const int*)d_in[23];
    float* out = (float*)d_out;
    float* ws = (float*)d_ws;

    float* wcat  = ws + WS_WCAT;
    float* gA    = ws + WS_GA;
    float* cbias = ws + WS_CBIAS;
    float* v1    = ws + WS_V1;
    float* v2    = ws + WS_V2;
    float* v3    = ws + WS_V3;
    float* cheff = ws + WS_CHEFF;
    float* c4    = ws + WS_C4;

    hipLaunchKernelGGL(k_prep, dim3(97), dim3(256), 0, stream, bw1, mw1, lng, mb1, lnb, pe,
                       chw, chb, phw, phb, bil, mob, pidx, wcat, gA, cbias, v1, v2, v3,
                       cheff, c4);
    hipLaunchKernelGGL(k_main, dim3(NT / TT), dim3(256), 0, stream, h, ex, lam, mup, bb1, bw2,
                       bb2, mw2, mb2, msw, sg, wcat, gA, cbias, v1, v2, v3, cheff, c4, out);
}

// Round 10
// 432.418 us; speedup vs baseline: 1.3193x; 1.1562x over previous
//
#include <hip/hip_runtime.h>
#include <hip/hip_bf16.h>
#include <cstdint>
#include <cstddef>

// ---------------------------------------------------------------------------
// Problem constants
// ---------------------------------------------------------------------------
#define NT      16384      // B*T tokens
#define DIM     768
#define TT      16         // tokens per block -> 1024 blocks
#define ALPHA_OFF 802816   // NT*49

// ws layout (floats). W is stored as MFMA B-fragments, bf16 hi+lo planes:
//   WF[plane][ks(24)][tile(32)][lane(64)][8 bf16]  -> 768 KB per plane.
#define WS_WFHI   0          // 196608 floats (768 KB as ushort pairs)
#define WS_WFLO   196608     // 196608 floats
#define WS_GA     393216     // 128
#define WS_CBIAS  393344     // 128
#define WS_V1     393472     // 128
#define WS_V2     393600     // 128
#define WS_V3     393728     // 128
#define WS_CHEFF  393856     // 512 (transposed [k][m])
#define WS_C4     394368     // 4

typedef __attribute__((ext_vector_type(8))) short short8;
typedef __attribute__((ext_vector_type(4))) float f32x4;

__device__ __forceinline__ float silu_f(float x) { return x / (1.0f + expf(-x)); }

__device__ __forceinline__ unsigned short f2bf_u(float x) {
    union { __hip_bfloat16 b; unsigned short u; } c;
    c.b = __float2bfloat16(x);
    return c.u;
}
__device__ __forceinline__ float bf2f_u(unsigned short u) {
    union { unsigned short u; __hip_bfloat16 b; } c;
    c.u = u;
    return __bfloat162float(c.b);
}

// ---------------------------------------------------------------------------
// Fused prep kernel, 97 blocks x 256 threads.
// Blocks 0..95: build W MFMA-fragments. Tile block (kt=bid>>3, jt=bid&7)
// covers k 64kt..+63 (ksteps 2kt..2kt+1), cols 64jt..+63 (N-tiles 4jt..4jt+3).
// W[k][col] sources: col<256: base_w1[col][k]; col<384: mlp_w1[col-256][k]*g[k];
// else mlp_w1[col-384][768+k]. Split w = hi + lo (bf16 RNE each).
// Fragment element (plane, ks, tile, lane l, j): W[ks*32+(l>>4)*8+j][tile*16+(l&15)]
// packed 8 bf16 = 16B at dst (ks*32+tile)*1024 + l*16 -> wave loads are
// lane-contiguous 1KB segments (perfectly coalesced).
// Block 96: small precomputes (gA, cbias, v1..v3, cheff_t, c4).
// ---------------------------------------------------------------------------
__global__ void k_prep(const float* __restrict__ bw1, const float* __restrict__ mw1,
                       const float* __restrict__ g, const float* __restrict__ mb1,
                       const float* __restrict__ lnb, const float* __restrict__ pe,
                       const float* __restrict__ chw, const float* __restrict__ chb,
                       const float* __restrict__ phw, const float* __restrict__ phb,
                       const float* __restrict__ bil, const float* __restrict__ mob,
                       const int* __restrict__ pidxp, unsigned int* __restrict__ wfh,
                       unsigned int* __restrict__ wfl,
                       float* __restrict__ gA, float* __restrict__ cbias,
                       float* __restrict__ v1, float* __restrict__ v2,
                       float* __restrict__ v3, float* __restrict__ cheff_t,
                       float* __restrict__ c4) {
    __shared__ float tilebuf[64][65];
    __shared__ float u[32];
    int tid = threadIdx.x;

    if (blockIdx.x == 96) {
        int pidx = *pidxp;
        if (tid < 32) u[tid] = pe[pidx * 32 + tid];
        __syncthreads();
        {
            int j = tid >> 1, half = tid & 1;
            const float* row = mw1 + (size_t)j * 1540 + half * 384;
            const float* gp = g + half * 384;
            const float* bp = lnb + half * 384;
            float sg_ = 0.f, sb_ = 0.f;
            for (int k = 0; k < 384; k += 4) {
                float4 rv = *(const float4*)(row + k);
                float4 gv = *(const float4*)(gp + k);
                float4 bv = *(const float4*)(bp + k);
                sg_ += rv.x * gv.x + rv.y * gv.y + rv.z * gv.z + rv.w * gv.w;
                sb_ += rv.x * bv.x + rv.y * bv.y + rv.z * bv.z + rv.w * bv.w;
            }
            sg_ += __shfl_xor(sg_, 1);
            sb_ += __shfl_xor(sb_, 1);
            if (half == 0) {
                const float* rowf = mw1 + (size_t)j * 1540;
                float pf = (float)pidx * (1.0f / 11.0f);
                gA[j] = sg_;
                v1[j] = rowf[1536];
                v2[j] = rowf[1537];
                v3[j] = rowf[1538];
                cbias[j] = sb_ + pf * rowf[1539] + mb1[j];
            }
        }
        for (int idx = tid; idx < 512; idx += 256) {
            int k = idx >> 2, m = idx & 3;
            float s = chw[m * 128 + k];
            for (int kk = 0; kk < 32; kk++) s += u[kk] * bil[(size_t)(m * 32 + kk) * 128 + k];
            cheff_t[k * 4 + m] = s;
        }
        if (tid < 4) {
            float s = chb[tid] + phb[tid] + mob[tid];
            for (int kk = 0; kk < 32; kk++) s += u[kk] * phw[tid * 32 + kk];
            c4[tid] = s;
        }
        return;
    }

    int jt = blockIdx.x & 7, kt = blockIdx.x >> 3;
    int j0 = jt * 64, k0 = kt * 64;

    {   // coalesced read: thread (jl, kc) reads 16 consecutive k of col j0+jl
        int jl = tid >> 2, kc = (tid & 3) * 16;
        int j = j0 + jl;
        const float* src;
        if (j0 < 256)      src = bw1 + (size_t)j * DIM + k0;
        else if (j0 < 384) src = mw1 + (size_t)(j - 256) * 1540 + k0;
        else               src = mw1 + (size_t)(j - 384) * 1540 + 768 + k0;
#pragma unroll
        for (int q = 0; q < 16; q += 4) {
            float4 v = *(const float4*)(src + kc + q);
            tilebuf[jl][kc + q + 0] = v.x;
            tilebuf[jl][kc + q + 1] = v.y;
            tilebuf[jl][kc + q + 2] = v.z;
            tilebuf[jl][kc + q + 3] = v.w;
        }
    }
    __syncthreads();
    {   // fragment pack: thread -> (lane l, ks_loc, 2 tiles)
        int l = tid & 63, item = tid >> 6;
        int ks_loc = item & 1, tp = item >> 1;
#pragma unroll
        for (int it = 0; it < 2; ++it) {
            int tile_loc = tp * 2 + it;
            int tile = jt * 4 + tile_loc;
            int ks = kt * 2 + ks_loc;
            int jl = tile_loc * 16 + (l & 15);
            int klb = ks_loc * 32 + (l >> 4) * 8;
            bool applyg = (tile >= 16 && tile < 24);
            unsigned int hiw[4], low[4];
#pragma unroll
            for (int p = 0; p < 4; ++p) {
                float x0 = tilebuf[jl][klb + 2 * p];
                float x1 = tilebuf[jl][klb + 2 * p + 1];
                if (applyg) {
                    x0 *= g[k0 + klb + 2 * p];
                    x1 *= g[k0 + klb + 2 * p + 1];
                }
                unsigned short h0 = f2bf_u(x0), h1 = f2bf_u(x1);
                unsigned short l0 = f2bf_u(x0 - bf2f_u(h0));
                unsigned short l1 = f2bf_u(x1 - bf2f_u(h1));
                hiw[p] = (unsigned int)h0 | ((unsigned int)h1 << 16);
                low[p] = (unsigned int)l0 | ((unsigned int)l1 << 16);
            }
            size_t idx = (size_t)(ks * 32 + tile) * 64 + l;
            ((uint4*)wfh)[idx] = make_uint4(hiw[0], hiw[1], hiw[2], hiw[3]);
            ((uint4*)wfl)[idx] = make_uint4(low[0], low[1], low[2], low[3]);
        }
    }
}

// ---------------------------------------------------------------------------
// A-staging: chunk = 64 k x 32 rows (16 h | 16 ex) fp32, layout [row][68]
// (stride 68 words -> ds b128 start banks 2-way max). Thread s: row=s>>3,
// seg=s&7 handles k seg*8..+7 (two float4): global reads 32B contiguous/row.
// ---------------------------------------------------------------------------
__device__ __forceinline__ void stage_ld2(const float* __restrict__ h,
                                          const float* __restrict__ ex,
                                          int tok0, int kb, int tid,
                                          float4& o0, float4& o1) {
    int row = tid >> 3, seg = tid & 7;
    const float* src = (row < 16) ? (h + (size_t)(tok0 + row) * DIM)
                                  : (ex + (size_t)(tok0 + row - 16) * DIM);
    o0 = *(const float4*)(src + kb + seg * 8);
    o1 = *(const float4*)(src + kb + seg * 8 + 4);
}
__device__ __forceinline__ void stage_st2(float* buf, int tid, float4 v0, float4 v1) {
    int row = tid >> 3, seg = tid & 7;
    float* d = buf + row * 68 + seg * 8;
    *(float4*)(d) = v0;
    *(float4*)(d + 4) = v1;
}

// ---------------------------------------------------------------------------
// Main fused kernel. 1024 blocks x 256 threads, 16 tokens per block.
// MAIN GEMM ON MATRIX CORES: mfma_f32_16x16x32_bf16, split-precision
// (w = wh + wl, a = ah + al; acc += ah*wh + ah*wl + al*wh -> fp32-like).
// Wave w owns N-tiles 8w..8w+7 (cols 128w..128w+127); per kstep (K=32):
// A-frag from LDS fp32 (lane: row=l&15 [+16 ex for w3], 8 k) -> hi/lo bf16;
// B-frags streamed from ws fragment arrays (1KB coalesced per tile).
// C/D layout (m89-verified): token m=(l>>4)*4+reg, col n=l&15.
// LDS F[8036] = 32.1 KB -> 4 blocks/CU, 4 waves/SIMD:
//   [0,4352)    : union { abuf[2][32*68] | a1[16][260] | cbuf[16][132] }
//   [4352,6464) : c1[16][132]
//   [6464,7248) : basebuf[16][49]
//   [7248,7376) : stats[16][8]
//   [7376,7888) : cheff_s[512]
//   [7888,7952) : alpha_s[16][4]
//   [7952,7956) : c4_s
//   [7956,7984) : msw_s[28]
//   [7984,8033) : sg_s[49] (ints)
// ---------------------------------------------------------------------------
__launch_bounds__(256, 4)
__global__ void k_main(const float* __restrict__ h, const float* __restrict__ ex,
                       const float* __restrict__ lam, const float* __restrict__ mup,
                       const float* __restrict__ bb1, const float* __restrict__ bw2,
                       const float* __restrict__ bb2, const float* __restrict__ mw2,
                       const float* __restrict__ mb2, const float* __restrict__ msw,
                       const int* __restrict__ sg, const unsigned int* __restrict__ wfh,
                       const unsigned int* __restrict__ wfl,
                       const float* __restrict__ gA, const float* __restrict__ cbias,
                       const float* __restrict__ v1w, const float* __restrict__ v2w,
                       const float* __restrict__ v3w, const float* __restrict__ cheff_t,
                       const float* __restrict__ c4, float* __restrict__ out) {
    __shared__ float F[8036];
    float* c1      = F + 4352;
    float* basebuf = F + 6464;
    float* stats   = F + 7248;
    float* cheff_s = F + 7376;
    float* alpha_s = F + 7888;
    float* c4_s    = F + 7952;
    float* msw_s   = F + 7956;
    int*   sg_s    = (int*)(F + 7984);

    const int tid = threadIdx.x;
    const int bid = blockIdx.x;
    const int tok0 = bid * TT;

    // --- small constant preloads ---
    if (tid < 49) sg_s[tid] = sg[tid];
    if (tid >= 64 && tid < 92) msw_s[tid - 64] = msw[tid - 64];
    if (tid >= 96 && tid < 100) c4_s[tid - 96] = c4[tid - 96];
    for (int i = tid; i < 512; i += 256) cheff_s[i] = cheff_t[i];

    // --- issue chunk-0 A staging loads early (latency hidden under stats) ---
    float4 p0, p1;
    stage_ld2(h, ex, tok0, 0, tid, p0, p1);

    // --- stats pass: 16 threads per token ---
    {
        int t = tid >> 4, r = tid & 15;
        const float* hp = h + (size_t)(tok0 + t) * DIM;
        const float* lp = lam + (size_t)(tok0 + t) * DIM;
        const float* mp = mup + (size_t)(tok0 + t) * DIM;
        float sh = 0.f, sh2 = 0.f, sll = 0.f, sll2 = 0.f, sd = 0.f;
        for (int i = 0; i < 12; i++) {
            int k0 = i * 64 + r * 4;
            float4 hv = *(const float4*)(hp + k0);
            float4 lv = *(const float4*)(lp + k0);
            float4 mv = *(const float4*)(mp + k0);
#pragma unroll
            for (int e = 0; e < 4; e++) {
                float hx = (&hv.x)[e];
                float lx = fmaxf((&lv.x)[e], 1e-6f);
                float mx = (&mv.x)[e];
                sh += hx; sh2 += hx * hx;
                float ll = logf(lx);
                sll += ll; sll2 += ll * ll;
                float dd = hx - mx; sd += dd * dd;
            }
        }
#pragma unroll
        for (int off = 1; off < 16; off <<= 1) {
            sh += __shfl_xor(sh, off);  sh2 += __shfl_xor(sh2, off);
            sll += __shfl_xor(sll, off); sll2 += __shfl_xor(sll2, off);
            sd += __shfl_xor(sd, off);
        }
        if (r == 0) {
            float m = sh * (1.f / 768.f);
            float var = sh2 * (1.f / 768.f) - m * m;
            float istd = rsqrtf(var + 1e-5f);
            float mll = sll * (1.f / 768.f);
            float vll = (sll2 - 768.f * mll * mll) * (1.f / 767.f);
            float sstd = fmaxf(sqrtf(fmaxf(vll, 0.f)), 1e-6f);
            float dmu = sqrtf(sd * (1.f / 768.f) + 1e-8f);
            float* st = stats + t * 8;
            st[0] = m; st[1] = istd; st[2] = mll; st[3] = sstd; st[4] = dmu;
        }
    }

    // --- write chunk-0 A into buffer 0 ---
    stage_st2(F, tid, p0, p1);
    __syncthreads();

    // --- main GEMM (MFMA): [16 tok] x [512 outs], K=768 ---
    const int w = tid >> 6, l = tid & 63;
    const int arowbase = (l & 15) + ((w == 3) ? 16 : 0);
    const int mrow0 = (l >> 4) * 4;
    const int q8 = (l >> 4) * 8;

    f32x4 acc[8];
#pragma unroll
    for (int t = 0; t < 8; ++t) acc[t] = (f32x4){0.f, 0.f, 0.f, 0.f};

    const short8* wph = (const short8*)wfh + (size_t)(8 * w) * 64 + l;
    const short8* wpl = (const short8*)wfl + (size_t)(8 * w) * 64 + l;

    int cur = 0;
    for (int c = 0; c < 12; ++c) {
        const bool more = (c + 1 < 12);
        const float* ab = F + cur * 2176;
        float* nb = F + (cur ^ 1) * 2176;
        if (more) stage_ld2(h, ex, tok0, (c + 1) * 64, tid, p0, p1);
#pragma unroll
        for (int ks_loc = 0; ks_loc < 2; ++ks_loc) {
            const int ks = c * 2 + ks_loc;
            const float* ar = ab + arowbase * 68 + ks_loc * 32 + q8;
            float4 a0  = *(const float4*)(ar);
            float4 a1v = *(const float4*)(ar + 4);
            float av[8] = {a0.x, a0.y, a0.z, a0.w, a1v.x, a1v.y, a1v.z, a1v.w};
            short8 Ah, Al;
#pragma unroll
            for (int j = 0; j < 8; ++j) {
                unsigned short hb = f2bf_u(av[j]);
                Ah[j] = (short)hb;
                Al[j] = (short)f2bf_u(av[j] - bf2f_u(hb));
            }
            const short8* bh = wph + (size_t)ks * 2048;
            const short8* bl = wpl + (size_t)ks * 2048;
#pragma unroll
            for (int t = 0; t < 8; ++t) {
                short8 Bh = bh[t * 64];
                short8 Bl = bl[t * 64];
                acc[t] = __builtin_amdgcn_mfma_f32_16x16x32_bf16(Ah, Bh, acc[t], 0, 0, 0);
                acc[t] = __builtin_amdgcn_mfma_f32_16x16x32_bf16(Ah, Bl, acc[t], 0, 0, 0);
                acc[t] = __builtin_amdgcn_mfma_f32_16x16x32_bf16(Al, Bh, acc[t], 0, 0, 0);
            }
        }
        if (more) stage_st2(nb, tid, p0, p1);
        __syncthreads();
        cur ^= 1;
    }

    // --- epilogue: lane holds token m=mrow0+r, col (8w+t)*16+(l&15) ---
    float* a1 = F;  // stride 260 (staging region dead)
    if (w < 2) {
#pragma unroll
        for (int t = 0; t < 8; ++t) {
            int j = (8 * w + t) * 16 + (l & 15);
            float b = bb1[j];
#pragma unroll
            for (int r = 0; r < 4; ++r)
                a1[(mrow0 + r) * 260 + j] = silu_f(acc[t][r] + b);
        }
    } else if (w == 2) {
#pragma unroll
        for (int t = 0; t < 8; ++t) {
            int jj = t * 16 + (l & 15);
            float ga = gA[jj], cb = cbias[jj];
            float w1 = v1w[jj], w2 = v2w[jj], w3 = v3w[jj];
#pragma unroll
            for (int r = 0; r < 4; ++r) {
                const float* st = stats + (mrow0 + r) * 8;
                c1[(mrow0 + r) * 132 + jj] =
                    st[1] * acc[t][r] - st[1] * st[0] * ga + st[2] * w1 + st[3] * w2 +
                    st[4] * w3 + cb;
            }
        }
    }
    __syncthreads();
    if (w == 3) {  // Q-side add + silu
#pragma unroll
        for (int t = 0; t < 8; ++t) {
            int jj = t * 16 + (l & 15);
#pragma unroll
            for (int r = 0; r < 4; ++r) {
                float* cp = &c1[(mrow0 + r) * 132 + jj];
                *cp = silu_f(*cp + acc[t][r]);
            }
        }
    }
    __syncthreads();

    // --- GEMM1b: base = a1 @ base_w2^T + b2  (16x49, K=256) ---
    for (int o = tid; o < TT * 49; o += 256) {
        int t = o / 49, s = o - t * 49;
        const float* ar = a1 + t * 260;
        const float* wr = bw2 + s * 256;
        float accv = bb2[s];
        for (int k = 0; k < 256; k += 4) {
            float4 av = *(const float4*)(ar + k);
            float4 wv = *(const float4*)(wr + k);
            accv += av.x * wv.x + av.y * wv.y + av.z * wv.z + av.w * wv.w;
        }
        basebuf[o] = accv;
    }
    __syncthreads();

    // --- GEMM2b: cmlp = c1 @ mlp_w2^T + b2 (16x128, K=128) -> cbuf (overlays a1) ---
    float* cbuf = F;  // stride 132
    {
        int j = tid & 127, tg = tid >> 7;
        float accv[8];
#pragma unroll
        for (int tt = 0; tt < 8; tt++) accv[tt] = 0.f;
        const float* wr = mw2 + (size_t)j * 128;
        const float* cr = c1 + tg * 8 * 132;
        for (int k = 0; k < 128; k += 4) {
            float4 wv = *(const float4*)(wr + k);
#pragma unroll
            for (int tt = 0; tt < 8; tt++) {
                float4 cv = *(const float4*)(cr + tt * 132 + k);
                accv[tt] += cv.x * wv.x + cv.y * wv.y + cv.z * wv.z + cv.w * wv.w;
            }
        }
        float b = mb2[j];
        __syncthreads();  // ensure all a1 reads (GEMM1b) done before overlay write
#pragma unroll
        for (int tt = 0; tt < 8; tt++) cbuf[(tg * 8 + tt) * 132 + j] = accv[tt] + b;
    }
    __syncthreads();

    // --- mode logits + softmax(4) -> alpha; write alpha to out ---
    if (tid < 64) {
        int t = tid >> 2, m = tid & 3;
        const float* cr = cbuf + t * 132;
        float e = c4_s[m];
        for (int k = 0; k < 128; k++) e += cr[k] * cheff_s[k * 4 + m];
        float mx = fmaxf(e, __shfl_xor(e, 1));
        mx = fmaxf(mx, __shfl_xor(mx, 2));
        float ev = expf(e - mx);
        float sum = ev + __shfl_xor(ev, 1);
        sum += __shfl_xor(sum, 2);
        float al = ev / sum;
        alpha_s[t * 4 + m] = al;
        out[ALPHA_OFF + (size_t)(tok0 + t) * 4 + m] = al;
    }
    __syncthreads();

    // --- K: masked stage-graph softmax over rows of 7 ---
    if (tid < TT * 7) {
        int t = tid / 7, i = tid - t * 7;
        const float* al = alpha_s + t * 4;
        float sb[7];
#pragma unroll
        for (int s = 0; s < 7; s++)
            sb[s] = al[0] * msw_s[s * 4 + 0] + al[1] * msw_s[s * 4 + 1] +
                    al[2] * msw_s[s * 4 + 2] + al[3] * msw_s[s * 4 + 3];
        const float* br = basebuf + t * 49 + i * 7;
        const int* mrow = sg_s + i * 7;
        float vals[7];
        float mx = -1e30f;
#pragma unroll
        for (int j = 0; j < 7; j++) {
            float vv = br[j] + sb[j];
            vals[j] = mrow[j] ? vv : -1e30f;
            mx = fmaxf(mx, vals[j]);
        }
        float e[7], sum = 0.f;
#pragma unroll
        for (int j = 0; j < 7; j++) {
            e[j] = mrow[j] ? expf(vals[j] - mx) : 0.f;
            sum += e[j];
        }
        float inv = 1.f / sum;
        size_t off = (size_t)(tok0 + t) * 49 + i * 7;
#pragma unroll
        for (int j = 0; j < 7; j++) out[off + j] = e[j] * inv;
    }
}

// ---------------------------------------------------------------------------
extern "C" void kernel_launch(void* const* d_in, const int* in_sizes, int n_in,
                              void* d_out, int out_size, void* d_ws, size_t ws_size,
                              hipStream_t stream) {
    const float* h    = (const float*)d_in[0];
    const float* ex   = (const float*)d_in[1];
    const float* lam  = (const float*)d_in[2];
    const float* mup  = (const float*)d_in[3];
    const float* bw1  = (const float*)d_in[4];
    const float* bb1  = (const float*)d_in[5];
    const float* bw2  = (const float*)d_in[6];
    const float* bb2  = (const float*)d_in[7];
    const float* lng  = (const float*)d_in[8];
    const float* lnb  = (const float*)d_in[9];
    const float* mw1  = (const float*)d_in[10];
    const float* mb1  = (const float*)d_in[11];
    const float* mw2  = (const float*)d_in[12];
    const float* mb2  = (const float*)d_in[13];
    const float* pe   = (const float*)d_in[14];
    const float* chw  = (const float*)d_in[15];
    const float* chb  = (const float*)d_in[16];
    const float* phw  = (const float*)d_in[17];
    const float* phb  = (const float*)d_in[18];
    const float* bil  = (const float*)d_in[19];
    const float* mob  = (const float*)d_in[20];
    const float* msw  = (const float*)d_in[21];
    const int*   sg   = (const int*)d_in[22];
    const int*   pidx = (const int*)d_in[23];
    float* out = (float*)d_out;
    float* ws = (float*)d_ws;

    unsigned int* wfh = (unsigned int*)(ws + WS_WFHI);
    unsigned int* wfl = (unsigned int*)(ws + WS_WFLO);
    float* gA    = ws + WS_GA;
    float* cbias = ws + WS_CBIAS;
    float* v1    = ws + WS_V1;
    float* v2    = ws + WS_V2;
    float* v3    = ws + WS_V3;
    float* cheff = ws + WS_CHEFF;
    float* c4    = ws + WS_C4;

    hipLaunchKernelGGL(k_prep, dim3(97), dim3(256), 0, stream, bw1, mw1, lng, mb1, lnb, pe,
                       chw, chb, phw, phb, bil, mob, pidx, wfh, wfl, gA, cbias, v1, v2, v3,
                       cheff, c4);
    hipLaunchKernelGGL(k_main, dim3(NT / TT), dim3(256), 0, stream, h, ex, lam, mup, bb1, bw2,
                       bb2, mw2, mb2, msw, sg, wfh, wfl, gA, cbias, v1, v2, v3, cheff, c4, out);
}

// Round 11
// 411.189 us; speedup vs baseline: 1.3874x; 1.0516x over previous
//
#include <hip/hip_runtime.h>
#include <hip/hip_bf16.h>
#include <cstdint>
#include <cstddef>

// ---------------------------------------------------------------------------
// Problem constants
// ---------------------------------------------------------------------------
#define NT      16384      // B*T tokens
#define DIM     768
#define TT      32         // tokens per block -> 512 blocks, 2/CU
#define ALPHA_OFF 802816   // NT*49

// ws layout (floats). W stored as MFMA B-fragments, bf16 hi+lo planes:
//   WF[plane][ks(24)][tile(32)][lane(64)][8 bf16]  -> 768 KB per plane.
#define WS_WFHI   0          // 196608 floats
#define WS_WFLO   196608     // 196608 floats
#define WS_GA     393216     // 128
#define WS_CBIAS  393344     // 128
#define WS_V1     393472     // 128
#define WS_V2     393600     // 128
#define WS_V3     393728     // 128
#define WS_CHEFF  393856     // 512 (transposed [k][m])
#define WS_C4     394368     // 4

typedef __attribute__((ext_vector_type(8))) short short8;
typedef __attribute__((ext_vector_type(4))) float f32x4;

__device__ __forceinline__ float silu_f(float x) { return x / (1.0f + expf(-x)); }

__device__ __forceinline__ unsigned short f2bf_u(float x) {
    union { __hip_bfloat16 b; unsigned short u; } c;
    c.b = __float2bfloat16(x);
    return c.u;
}
__device__ __forceinline__ float bf2f_u(unsigned short u) {
    union { unsigned short u; __hip_bfloat16 b; } c;
    c.u = u;
    return __bfloat162float(c.b);
}

// ---------------------------------------------------------------------------
// Fused prep kernel, 97 blocks x 256 threads.  (UNCHANGED from round 9)
// Blocks 0..95: build W MFMA B-fragments (hi/lo bf16 planes), tile block
// (kt=bid>>3, jt=bid&7) covers k 64kt..+63 (ksteps 2kt..2kt+1), cols
// 64jt..+63 (N-tiles 4jt..4jt+3). Sources: col<256: base_w1[col][k];
// col<384: mlp_w1[col-256][k]*g[k]; else mlp_w1[col-384][768+k].
// Fragment: (ks,tile,lane l,j) = W[ks*32+(l>>4)*8+j][tile*16+(l&15)],
// 16B per lane at (ks*32+tile)*1024 + l*16 -> 1KB coalesced wave loads.
// Block 96: small precomputes (gA, cbias, v1..v3, cheff_t, c4).
// ---------------------------------------------------------------------------
__global__ void k_prep(const float* __restrict__ bw1, const float* __restrict__ mw1,
                       const float* __restrict__ g, const float* __restrict__ mb1,
                       const float* __restrict__ lnb, const float* __restrict__ pe,
                       const float* __restrict__ chw, const float* __restrict__ chb,
                       const float* __restrict__ phw, const float* __restrict__ phb,
                       const float* __restrict__ bil, const float* __restrict__ mob,
                       const int* __restrict__ pidxp, unsigned int* __restrict__ wfh,
                       unsigned int* __restrict__ wfl,
                       float* __restrict__ gA, float* __restrict__ cbias,
                       float* __restrict__ v1, float* __restrict__ v2,
                       float* __restrict__ v3, float* __restrict__ cheff_t,
                       float* __restrict__ c4) {
    __shared__ float tilebuf[64][65];
    __shared__ float u[32];
    int tid = threadIdx.x;

    if (blockIdx.x == 96) {
        int pidx = *pidxp;
        if (tid < 32) u[tid] = pe[pidx * 32 + tid];
        __syncthreads();
        {
            int j = tid >> 1, half = tid & 1;
            const float* row = mw1 + (size_t)j * 1540 + half * 384;
            const float* gp = g + half * 384;
            const float* bp = lnb + half * 384;
            float sg_ = 0.f, sb_ = 0.f;
            for (int k = 0; k < 384; k += 4) {
                float4 rv = *(const float4*)(row + k);
                float4 gv = *(const float4*)(gp + k);
                float4 bv = *(const float4*)(bp + k);
                sg_ += rv.x * gv.x + rv.y * gv.y + rv.z * gv.z + rv.w * gv.w;
                sb_ += rv.x * bv.x + rv.y * bv.y + rv.z * bv.z + rv.w * bv.w;
            }
            sg_ += __shfl_xor(sg_, 1);
            sb_ += __shfl_xor(sb_, 1);
            if (half == 0) {
                const float* rowf = mw1 + (size_t)j * 1540;
                float pf = (float)pidx * (1.0f / 11.0f);
                gA[j] = sg_;
                v1[j] = rowf[1536];
                v2[j] = rowf[1537];
                v3[j] = rowf[1538];
                cbias[j] = sb_ + pf * rowf[1539] + mb1[j];
            }
        }
        for (int idx = tid; idx < 512; idx += 256) {
            int k = idx >> 2, m = idx & 3;
            float s = chw[m * 128 + k];
            for (int kk = 0; kk < 32; kk++) s += u[kk] * bil[(size_t)(m * 32 + kk) * 128 + k];
            cheff_t[k * 4 + m] = s;
        }
        if (tid < 4) {
            float s = chb[tid] + phb[tid] + mob[tid];
            for (int kk = 0; kk < 32; kk++) s += u[kk] * phw[tid * 32 + kk];
            c4[tid] = s;
        }
        return;
    }

    int jt = blockIdx.x & 7, kt = blockIdx.x >> 3;
    int j0 = jt * 64, k0 = kt * 64;

    {   // coalesced read: thread (jl, kc) reads 16 consecutive k of col j0+jl
        int jl = tid >> 2, kc = (tid & 3) * 16;
        int j = j0 + jl;
        const float* src;
        if (j0 < 256)      src = bw1 + (size_t)j * DIM + k0;
        else if (j0 < 384) src = mw1 + (size_t)(j - 256) * 1540 + k0;
        else               src = mw1 + (size_t)(j - 384) * 1540 + 768 + k0;
#pragma unroll
        for (int q = 0; q < 16; q += 4) {
            float4 v = *(const float4*)(src + kc + q);
            tilebuf[jl][kc + q + 0] = v.x;
            tilebuf[jl][kc + q + 1] = v.y;
            tilebuf[jl][kc + q + 2] = v.z;
            tilebuf[jl][kc + q + 3] = v.w;
        }
    }
    __syncthreads();
    {   // fragment pack: thread -> (lane l, ks_loc, 2 tiles)
        int l = tid & 63, item = tid >> 6;
        int ks_loc = item & 1, tp = item >> 1;
#pragma unroll
        for (int it = 0; it < 2; ++it) {
            int tile_loc = tp * 2 + it;
            int tile = jt * 4 + tile_loc;
            int ks = kt * 2 + ks_loc;
            int jl = tile_loc * 16 + (l & 15);
            int klb = ks_loc * 32 + (l >> 4) * 8;
            bool applyg = (tile >= 16 && tile < 24);
            unsigned int hiw[4], low[4];
#pragma unroll
            for (int p = 0; p < 4; ++p) {
                float x0 = tilebuf[jl][klb + 2 * p];
                float x1 = tilebuf[jl][klb + 2 * p + 1];
                if (applyg) {
                    x0 *= g[k0 + klb + 2 * p];
                    x1 *= g[k0 + klb + 2 * p + 1];
                }
                unsigned short h0 = f2bf_u(x0), h1 = f2bf_u(x1);
                unsigned short l0 = f2bf_u(x0 - bf2f_u(h0));
                unsigned short l1 = f2bf_u(x1 - bf2f_u(h1));
                hiw[p] = (unsigned int)h0 | ((unsigned int)h1 << 16);
                low[p] = (unsigned int)l0 | ((unsigned int)l1 << 16);
            }
            size_t idx = (size_t)(ks * 32 + tile) * 64 + l;
            ((uint4*)wfh)[idx] = make_uint4(hiw[0], hiw[1], hiw[2], hiw[3]);
            ((uint4*)wfl)[idx] = make_uint4(low[0], low[1], low[2], low[3]);
        }
    }
}

// ---------------------------------------------------------------------------
// A-staging (TT=32): chunk = 64 k x 64 rows (32 h | 32 ex) fp32, [row][68].
// Thread s: row=s>>2 (0..63), seg=s&3 -> k seg*16..+15 (4 float4):
// global reads 64B contiguous per thread, 4 threads cover a row segment.
// ---------------------------------------------------------------------------
__device__ __forceinline__ void stage_ld4(const float* __restrict__ h,
                                          const float* __restrict__ ex,
                                          int tok0, int kb, int tid, float4 o[4]) {
    int row = tid >> 2, seg = tid & 3;
    const float* src = (row < 32) ? (h + (size_t)(tok0 + row) * DIM)
                                  : (ex + (size_t)(tok0 + row - 32) * DIM);
    const float* p = src + kb + seg * 16;
    o[0] = *(const float4*)(p);
    o[1] = *(const float4*)(p + 4);
    o[2] = *(const float4*)(p + 8);
    o[3] = *(const float4*)(p + 12);
}
__device__ __forceinline__ void stage_st4(float* buf, int tid, const float4 o[4]) {
    int row = tid >> 2, seg = tid & 3;
    float* d = buf + row * 68 + seg * 16;
    *(float4*)(d) = o[0];
    *(float4*)(d + 4) = o[1];
    *(float4*)(d + 8) = o[2];
    *(float4*)(d + 12) = o[3];
}

// ---------------------------------------------------------------------------
// Main fused kernel. 512 blocks x 256 threads, 32 tokens per block (2/CU).
// MFMA split-precision GEMM; wave w owns N-tiles 8w..8w+7 AND BOTH M-tiles
// (tokens 0-15, 16-31) -> each B-fragment feeds 2 M-tiles: per-block B
// traffic 1.5MB, total 0.77GB (half of R10). Per kstep: issue ALL 16 B-frag
// loads first (BH/BL, statically indexed), then A ds_reads + hi/lo convert
// (covers B latency), then 48 MFMAs. acc[2][8] f32x4; VGPR budget free
// (2 waves/SIMD cap from grid).
// LDS F[15473] = 61.9 KB:
//   [0,8704)       : union { abuf[2][64*68] | a1[32][260] | cbuf[32][132] }
//   [8704,12928)   : c1[32][132]
//   [12928,14496)  : basebuf[32][49]
//   [14496,14752)  : stats[32][8]
//   [14752,15264)  : cheff_s[512]
//   [15264,15392)  : alpha_s[32][4]
//   [15392,15396)  : c4_s
//   [15396,15424)  : msw_s[28]
//   [15424,15473)  : sg_s[49] (ints)
// ---------------------------------------------------------------------------
__launch_bounds__(256, 2)
__global__ void k_main(const float* __restrict__ h, const float* __restrict__ ex,
                       const float* __restrict__ lam, const float* __restrict__ mup,
                       const float* __restrict__ bb1, const float* __restrict__ bw2,
                       const float* __restrict__ bb2, const float* __restrict__ mw2,
                       const float* __restrict__ mb2, const float* __restrict__ msw,
                       const int* __restrict__ sg, const unsigned int* __restrict__ wfh,
                       const unsigned int* __restrict__ wfl,
                       const float* __restrict__ gA, const float* __restrict__ cbias,
                       const float* __restrict__ v1w, const float* __restrict__ v2w,
                       const float* __restrict__ v3w, const float* __restrict__ cheff_t,
                       const float* __restrict__ c4, float* __restrict__ out) {
    __shared__ float F[15473];
    float* c1      = F + 8704;
    float* basebuf = F + 12928;
    float* stats   = F + 14496;
    float* cheff_s = F + 14752;
    float* alpha_s = F + 15264;
    float* c4_s    = F + 15392;
    float* msw_s   = F + 15396;
    int*   sg_s    = (int*)(F + 15424);

    const int tid = threadIdx.x;
    const int bid = blockIdx.x;
    const int tok0 = bid * TT;

    // --- small constant preloads ---
    if (tid < 49) sg_s[tid] = sg[tid];
    if (tid >= 64 && tid < 92) msw_s[tid - 64] = msw[tid - 64];
    if (tid >= 96 && tid < 100) c4_s[tid - 96] = c4[tid - 96];
    for (int i = tid; i < 512; i += 256) cheff_s[i] = cheff_t[i];

    // --- issue chunk-0 A staging loads early (latency hidden under stats) ---
    float4 p[4];
    stage_ld4(h, ex, tok0, 0, tid, p);

    // --- stats pass: 8 threads per token ---
    {
        int t = tid >> 3, r = tid & 7;
        const float* hp = h + (size_t)(tok0 + t) * DIM;
        const float* lp = lam + (size_t)(tok0 + t) * DIM;
        const float* mp = mup + (size_t)(tok0 + t) * DIM;
        float sh = 0.f, sh2 = 0.f, sll = 0.f, sll2 = 0.f, sd = 0.f;
        for (int i = 0; i < 24; i++) {
            int k0 = i * 32 + r * 4;
            float4 hv = *(const float4*)(hp + k0);
            float4 lv = *(const float4*)(lp + k0);
            float4 mv = *(const float4*)(mp + k0);
#pragma unroll
            for (int e = 0; e < 4; e++) {
                float hx = (&hv.x)[e];
                float lx = fmaxf((&lv.x)[e], 1e-6f);
                float mx = (&mv.x)[e];
                sh += hx; sh2 += hx * hx;
                float ll = logf(lx);
                sll += ll; sll2 += ll * ll;
                float dd = hx - mx; sd += dd * dd;
            }
        }
#pragma unroll
        for (int off = 1; off < 8; off <<= 1) {
            sh += __shfl_xor(sh, off);  sh2 += __shfl_xor(sh2, off);
            sll += __shfl_xor(sll, off); sll2 += __shfl_xor(sll2, off);
            sd += __shfl_xor(sd, off);
        }
        if (r == 0) {
            float m = sh * (1.f / 768.f);
            float var = sh2 * (1.f / 768.f) - m * m;
            float istd = rsqrtf(var + 1e-5f);
            float mll = sll * (1.f / 768.f);
            float vll = (sll2 - 768.f * mll * mll) * (1.f / 767.f);
            float sstd = fmaxf(sqrtf(fmaxf(vll, 0.f)), 1e-6f);
            float dmu = sqrtf(sd * (1.f / 768.f) + 1e-8f);
            float* st = stats + t * 8;
            st[0] = m; st[1] = istd; st[2] = mll; st[3] = sstd; st[4] = dmu;
        }
    }

    // --- write chunk-0 A into buffer 0 ---
    stage_st4(F, tid, p);
    __syncthreads();

    // --- main GEMM (MFMA): [32 tok] x [512 outs], K=768 ---
    const int w = tid >> 6, l = tid & 63;
    const int lm = l & 15, lk = l >> 4;
    const int abase = ((w == 3) ? 32 : 0) + lm;  // row of M-tile 0
    const int q8 = lk * 8;

    f32x4 acc[2][8];
#pragma unroll
    for (int m = 0; m < 2; ++m)
#pragma unroll
        for (int t = 0; t < 8; ++t) acc[m][t] = (f32x4){0.f, 0.f, 0.f, 0.f};

    const short8* wph = (const short8*)wfh + (size_t)(8 * w) * 64 + l;
    const short8* wpl = (const short8*)wfl + (size_t)(8 * w) * 64 + l;

    int cur = 0;
    for (int c = 0; c < 12; ++c) {
        const bool more = (c + 1 < 12);
        const float* ab = F + cur * 4352;
        float* nb = F + (cur ^ 1) * 4352;
        if (more) stage_ld4(h, ex, tok0, (c + 1) * 64, tid, p);
#pragma unroll
        for (int ks_loc = 0; ks_loc < 2; ++ks_loc) {
            const int ks = c * 2 + ks_loc;
            const short8* bh = wph + (size_t)ks * 2048;
            const short8* bl = wpl + (size_t)ks * 2048;
            // 1) issue ALL 16 B-fragment loads (statically indexed regs)
            short8 BH[8], BL[8];
#pragma unroll
            for (int t = 0; t < 8; ++t) {
                BH[t] = bh[t * 64];
                BL[t] = bl[t * 64];
            }
            // 2) A ds_reads + hi/lo converts (covers B-load latency)
            const float* ar0 = ab + abase * 68 + ks_loc * 32 + q8;
            const float* ar1 = ar0 + 16 * 68;
            float4 a00 = *(const float4*)(ar0);
            float4 a01 = *(const float4*)(ar0 + 4);
            float4 a10 = *(const float4*)(ar1);
            float4 a11 = *(const float4*)(ar1 + 4);
            float av0[8] = {a00.x, a00.y, a00.z, a00.w, a01.x, a01.y, a01.z, a01.w};
            float av1[8] = {a10.x, a10.y, a10.z, a10.w, a11.x, a11.y, a11.z, a11.w};
            short8 Ah0, Al0, Ah1, Al1;
#pragma unroll
            for (int j = 0; j < 8; ++j) {
                unsigned short hb0 = f2bf_u(av0[j]);
                Ah0[j] = (short)hb0;
                Al0[j] = (short)f2bf_u(av0[j] - bf2f_u(hb0));
                unsigned short hb1 = f2bf_u(av1[j]);
                Ah1[j] = (short)hb1;
                Al1[j] = (short)f2bf_u(av1[j] - bf2f_u(hb1));
            }
            // 3) 48 MFMAs (16 independent 3-chains)
#pragma unroll
            for (int t = 0; t < 8; ++t) {
                acc[0][t] = __builtin_amdgcn_mfma_f32_16x16x32_bf16(Ah0, BH[t], acc[0][t], 0, 0, 0);
                acc[1][t] = __builtin_amdgcn_mfma_f32_16x16x32_bf16(Ah1, BH[t], acc[1][t], 0, 0, 0);
                acc[0][t] = __builtin_amdgcn_mfma_f32_16x16x32_bf16(Ah0, BL[t], acc[0][t], 0, 0, 0);
                acc[1][t] = __builtin_amdgcn_mfma_f32_16x16x32_bf16(Ah1, BL[t], acc[1][t], 0, 0, 0);
                acc[0][t] = __builtin_amdgcn_mfma_f32_16x16x32_bf16(Al0, BH[t], acc[0][t], 0, 0, 0);
                acc[1][t] = __builtin_amdgcn_mfma_f32_16x16x32_bf16(Al1, BH[t], acc[1][t], 0, 0, 0);
            }
        }
        if (more) stage_st4(nb, tid, p);
        __syncthreads();
        cur ^= 1;
    }

    // --- epilogue: lane holds token M*16 + lk*4 + r, col (8w+t)*16 + lm ---
    float* a1 = F;  // stride 260 (staging region dead)
    if (w < 2) {
#pragma unroll
        for (int t = 0; t < 8; ++t) {
            int j = (8 * w + t) * 16 + lm;
            float b = bb1[j];
#pragma unroll
            for (int m = 0; m < 2; ++m)
#pragma unroll
                for (int r = 0; r < 4; ++r)
                    a1[(m * 16 + lk * 4 + r) * 260 + j] = silu_f(acc[m][t][r] + b);
        }
    } else if (w == 2) {
#pragma unroll
        for (int t = 0; t < 8; ++t) {
            int jj = t * 16 + lm;
            float ga = gA[jj], cb = cbias[jj];
            float w1 = v1w[jj], w2 = v2w[jj], w3 = v3w[jj];
#pragma unroll
            for (int m = 0; m < 2; ++m)
#pragma unroll
                for (int r = 0; r < 4; ++r) {
                    int tok = m * 16 + lk * 4 + r;
                    const float* st = stats + tok * 8;
                    c1[tok * 132 + jj] =
                        st[1] * acc[m][t][r] - st[1] * st[0] * ga + st[2] * w1 +
                        st[3] * w2 + st[4] * w3 + cb;
                }
        }
    }
    __syncthreads();
    if (w == 3) {  // Q-side add + silu
#pragma unroll
        for (int t = 0; t < 8; ++t) {
            int jj = t * 16 + lm;
#pragma unroll
            for (int m = 0; m < 2; ++m)
#pragma unroll
                for (int r = 0; r < 4; ++r) {
                    int tok = m * 16 + lk * 4 + r;
                    float* cp = &c1[tok * 132 + jj];
                    *cp = silu_f(*cp + acc[m][t][r]);
                }
        }
    }
    __syncthreads();

    // --- GEMM1b: base = a1 @ base_w2^T + b2  (32x49, K=256) ---
    for (int o = tid; o < TT * 49; o += 256) {
        int t = o / 49, s = o - t * 49;
        const float* ar = a1 + t * 260;
        const float* wr = bw2 + s * 256;
        float accv = bb2[s];
        for (int k = 0; k < 256; k += 4) {
            float4 av = *(const float4*)(ar + k);
            float4 wv = *(const float4*)(wr + k);
            accv += av.x * wv.x + av.y * wv.y + av.z * wv.z + av.w * wv.w;
        }
        basebuf[o] = accv;
    }
    __syncthreads();

    // --- GEMM2b: cmlp = c1 @ mlp_w2^T + b2 (32x128, K=128) -> cbuf (overlays a1) ---
    float* cbuf = F;  // stride 132
    {
        int j = tid & 127, tg = tid >> 7;
        float accv[16];
#pragma unroll
        for (int tt = 0; tt < 16; tt++) accv[tt] = 0.f;
        const float* wr = mw2 + (size_t)j * 128;
        const float* cr = c1 + tg * 16 * 132;
        for (int k = 0; k < 128; k += 4) {
            float4 wv = *(const float4*)(wr + k);
#pragma unroll
            for (int tt = 0; tt < 16; tt++) {
                float4 cv = *(const float4*)(cr + tt * 132 + k);
                accv[tt] += cv.x * wv.x + cv.y * wv.y + cv.z * wv.z + cv.w * wv.w;
            }
        }
        float b = mb2[j];
        __syncthreads();  // ensure all a1 reads (GEMM1b) done before overlay write
#pragma unroll
        for (int tt = 0; tt < 16; tt++) cbuf[(tg * 16 + tt) * 132 + j] = accv[tt] + b;
    }
    __syncthreads();

    // --- mode logits + softmax(4) -> alpha; write alpha to out ---
    if (tid < 128) {
        int t = tid >> 2, m = tid & 3;
        const float* cr = cbuf + t * 132;
        float e = c4_s[m];
        for (int k = 0; k < 128; k++) e += cr[k] * cheff_s[k * 4 + m];
        float mx = fmaxf(e, __shfl_xor(e, 1));
        mx = fmaxf(mx, __shfl_xor(mx, 2));
        float ev = expf(e - mx);
        float sum = ev + __shfl_xor(ev, 1);
        sum += __shfl_xor(sum, 2);
        float al = ev / sum;
        alpha_s[t * 4 + m] = al;
        out[ALPHA_OFF + (size_t)(tok0 + t) * 4 + m] = al;
    }
    __syncthreads();

    // --- K: masked stage-graph softmax over rows of 7 ---
    if (tid < TT * 7) {
        int t = tid / 7, i = tid - t * 7;
        const float* al = alpha_s + t * 4;
        float sb[7];
#pragma unroll
        for (int s = 0; s < 7; s++)
            sb[s] = al[0] * msw_s[s * 4 + 0] + al[1] * msw_s[s * 4 + 1] +
                    al[2] * msw_s[s * 4 + 2] + al[3] * msw_s[s * 4 + 3];
        const float* br = basebuf + t * 49 + i * 7;
        const int* mrow = sg_s + i * 7;
        float vals[7];
        float mx = -1e30f;
#pragma unroll
        for (int j = 0; j < 7; j++) {
            float vv = br[j] + sb[j];
            vals[j] = mrow[j] ? vv : -1e30f;
            mx = fmaxf(mx, vals[j]);
        }
        float e[7], sum = 0.f;
#pragma unroll
        for (int j = 0; j < 7; j++) {
            e[j] = mrow[j] ? expf(vals[j] - mx) : 0.f;
            sum += e[j];
        }
        float inv = 1.f / sum;
        size_t off = (size_t)(tok0 + t) * 49 + i * 7;
#pragma unroll
        for (int j = 0; j < 7; j++) out[off + j] = e[j] * inv;
    }
}

// ---------------------------------------------------------------------------
extern "C" void kernel_launch(void* const* d_in, const int* in_sizes, int n_in,
                              void* d_out, int out_size, void* d_ws, size_t ws_size,
                              hipStream_t stream) {
    const float* h    = (const float*)d_in[0];
    const float* ex   = (const float*)d_in[1];
    const float* lam  = (const float*)d_in[2];
    const float* mup  = (const float*)d_in[3];
    const float* bw1  = (const float*)d_in[4];
    const float* bb1  = (const float*)d_in[5];
    const float* bw2  = (const float*)d_in[6];
    const float* bb2  = (const float*)d_in[7];
    const float* lng  = (const float*)d_in[8];
    const float* lnb  = (const float*)d_in[9];
    const float* mw1  = (const float*)d_in[10];
    const float* mb1  = (const float*)d_in[11];
    const float* mw2  = (const float*)d_in[12];
    const float* mb2  = (const float*)d_in[13];
    const float* pe   = (const float*)d_in[14];
    const float* chw  = (const float*)d_in[15];
    const float* chb  = (const float*)d_in[16];
    const float* phw  = (const float*)d_in[17];
    const float* phb  = (const float*)d_in[18];
    const float* bil  = (const float*)d_in[19];
    const float* mob  = (const float*)d_in[20];
    const float* msw  = (const float*)d_in[21];
    const int*   sg   = (const int*)d_in[22];
    const int*   pidx = (const int*)d_in[23];
    float* out = (float*)d_out;
    float* ws = (float*)d_ws;

    unsigned int* wfh = (unsigned int*)(ws + WS_WFHI);
    unsigned int* wfl = (unsigned int*)(ws + WS_WFLO);
    float* gA    = ws + WS_GA;
    float* cbias = ws + WS_CBIAS;
    float* v1    = ws + WS_V1;
    float* v2    = ws + WS_V2;
    float* v3    = ws + WS_V3;
    float* cheff = ws + WS_CHEFF;
    float* c4    = ws + WS_C4;

    hipLaunchKernelGGL(k_prep, dim3(97), dim3(256), 0, stream, bw1, mw1, lng, mb1, lnb, pe,
                       chw, chb, phw, phb, bil, mob, pidx, wfh, wfl, gA, cbias, v1, v2, v3,
                       cheff, c4);
    hipLaunchKernelGGL(k_main, dim3(NT / TT), dim3(256), 0, stream, h, ex, lam, mup, bb1, bw2,
                       bb2, mw2, mb2, msw, sg, wfh, wfl, gA, cbias, v1, v2, v3, cheff, c4, out);
}

// Round 12
// 373.240 us; speedup vs baseline: 1.5285x; 1.1017x over previous
//
#include <hip/hip_runtime.h>
#include <hip/hip_bf16.h>
#include <cstdint>
#include <cstddef>

// ---------------------------------------------------------------------------
// Problem constants
// ---------------------------------------------------------------------------
#define NT      16384      // B*T tokens
#define DIM     768
#define TT      32         // tokens per block -> 512 blocks, 2/CU
#define ALPHA_OFF 802816   // NT*49

// ws layout (floats). W stored as MFMA B-fragments, bf16 hi+lo planes:
//   WF[plane][ks(24)][tile(32)][lane(64)][8 bf16]  -> 768 KB per plane.
#define WS_WFHI   0          // 196608 floats
#define WS_WFLO   196608     // 196608 floats
#define WS_GA     393216     // 128
#define WS_CBIAS  393344     // 128
#define WS_V1     393472     // 128
#define WS_V2     393600     // 128
#define WS_V3     393728     // 128
#define WS_CHEFF  393856     // 512 (transposed [k][m])
#define WS_C4     394368     // 4

typedef __attribute__((ext_vector_type(8))) short short8;
typedef __attribute__((ext_vector_type(4))) float f32x4;

__device__ __forceinline__ float silu_f(float x) { return x / (1.0f + expf(-x)); }

__device__ __forceinline__ unsigned short f2bf_u(float x) {
    union { __hip_bfloat16 b; unsigned short u; } c;
    c.b = __float2bfloat16(x);
    return c.u;
}
__device__ __forceinline__ float bf2f_u(unsigned short u) {
    union { unsigned short u; __hip_bfloat16 b; } c;
    c.u = u;
    return __bfloat162float(c.b);
}

// ---------------------------------------------------------------------------
// Fused prep kernel, 97 blocks x 256 threads.  (UNCHANGED)
// Blocks 0..95: build W MFMA B-fragments (hi/lo bf16 planes), tile block
// (kt=bid>>3, jt=bid&7) covers k 64kt..+63 (ksteps 2kt..2kt+1), cols
// 64jt..+63 (N-tiles 4jt..4jt+3). Sources: col<256: base_w1[col][k];
// col<384: mlp_w1[col-256][k]*g[k]; else mlp_w1[col-384][768+k].
// Fragment: (ks,tile,lane l,j) = W[ks*32+(l>>4)*8+j][tile*16+(l&15)],
// 16B per lane at (ks*32+tile)*1024 + l*16 -> 1KB coalesced wave loads.
// Block 96: small precomputes (gA, cbias, v1..v3, cheff_t, c4).
// ---------------------------------------------------------------------------
__global__ void k_prep(const float* __restrict__ bw1, const float* __restrict__ mw1,
                       const float* __restrict__ g, const float* __restrict__ mb1,
                       const float* __restrict__ lnb, const float* __restrict__ pe,
                       const float* __restrict__ chw, const float* __restrict__ chb,
                       const float* __restrict__ phw, const float* __restrict__ phb,
                       const float* __restrict__ bil, const float* __restrict__ mob,
                       const int* __restrict__ pidxp, unsigned int* __restrict__ wfh,
                       unsigned int* __restrict__ wfl,
                       float* __restrict__ gA, float* __restrict__ cbias,
                       float* __restrict__ v1, float* __restrict__ v2,
                       float* __restrict__ v3, float* __restrict__ cheff_t,
                       float* __restrict__ c4) {
    __shared__ float tilebuf[64][65];
    __shared__ float u[32];
    int tid = threadIdx.x;

    if (blockIdx.x == 96) {
        int pidx = *pidxp;
        if (tid < 32) u[tid] = pe[pidx * 32 + tid];
        __syncthreads();
        {
            int j = tid >> 1, half = tid & 1;
            const float* row = mw1 + (size_t)j * 1540 + half * 384;
            const float* gp = g + half * 384;
            const float* bp = lnb + half * 384;
            float sg_ = 0.f, sb_ = 0.f;
            for (int k = 0; k < 384; k += 4) {
                float4 rv = *(const float4*)(row + k);
                float4 gv = *(const float4*)(gp + k);
                float4 bv = *(const float4*)(bp + k);
                sg_ += rv.x * gv.x + rv.y * gv.y + rv.z * gv.z + rv.w * gv.w;
                sb_ += rv.x * bv.x + rv.y * bv.y + rv.z * bv.z + rv.w * bv.w;
            }
            sg_ += __shfl_xor(sg_, 1);
            sb_ += __shfl_xor(sb_, 1);
            if (half == 0) {
                const float* rowf = mw1 + (size_t)j * 1540;
                float pf = (float)pidx * (1.0f / 11.0f);
                gA[j] = sg_;
                v1[j] = rowf[1536];
                v2[j] = rowf[1537];
                v3[j] = rowf[1538];
                cbias[j] = sb_ + pf * rowf[1539] + mb1[j];
            }
        }
        for (int idx = tid; idx < 512; idx += 256) {
            int k = idx >> 2, m = idx & 3;
            float s = chw[m * 128 + k];
            for (int kk = 0; kk < 32; kk++) s += u[kk] * bil[(size_t)(m * 32 + kk) * 128 + k];
            cheff_t[k * 4 + m] = s;
        }
        if (tid < 4) {
            float s = chb[tid] + phb[tid] + mob[tid];
            for (int kk = 0; kk < 32; kk++) s += u[kk] * phw[tid * 32 + kk];
            c4[tid] = s;
        }
        return;
    }

    int jt = blockIdx.x & 7, kt = blockIdx.x >> 3;
    int j0 = jt * 64, k0 = kt * 64;

    {   // coalesced read: thread (jl, kc) reads 16 consecutive k of col j0+jl
        int jl = tid >> 2, kc = (tid & 3) * 16;
        int j = j0 + jl;
        const float* src;
        if (j0 < 256)      src = bw1 + (size_t)j * DIM + k0;
        else if (j0 < 384) src = mw1 + (size_t)(j - 256) * 1540 + k0;
        else               src = mw1 + (size_t)(j - 384) * 1540 + 768 + k0;
#pragma unroll
        for (int q = 0; q < 16; q += 4) {
            float4 v = *(const float4*)(src + kc + q);
            tilebuf[jl][kc + q + 0] = v.x;
            tilebuf[jl][kc + q + 1] = v.y;
            tilebuf[jl][kc + q + 2] = v.z;
            tilebuf[jl][kc + q + 3] = v.w;
        }
    }
    __syncthreads();
    {   // fragment pack: thread -> (lane l, ks_loc, 2 tiles)
        int l = tid & 63, item = tid >> 6;
        int ks_loc = item & 1, tp = item >> 1;
#pragma unroll
        for (int it = 0; it < 2; ++it) {
            int tile_loc = tp * 2 + it;
            int tile = jt * 4 + tile_loc;
            int ks = kt * 2 + ks_loc;
            int jl = tile_loc * 16 + (l & 15);
            int klb = ks_loc * 32 + (l >> 4) * 8;
            bool applyg = (tile >= 16 && tile < 24);
            unsigned int hiw[4], low[4];
#pragma unroll
            for (int p = 0; p < 4; ++p) {
                float x0 = tilebuf[jl][klb + 2 * p];
                float x1 = tilebuf[jl][klb + 2 * p + 1];
                if (applyg) {
                    x0 *= g[k0 + klb + 2 * p];
                    x1 *= g[k0 + klb + 2 * p + 1];
                }
                unsigned short h0 = f2bf_u(x0), h1 = f2bf_u(x1);
                unsigned short l0 = f2bf_u(x0 - bf2f_u(h0));
                unsigned short l1 = f2bf_u(x1 - bf2f_u(h1));
                hiw[p] = (unsigned int)h0 | ((unsigned int)h1 << 16);
                low[p] = (unsigned int)l0 | ((unsigned int)l1 << 16);
            }
            size_t idx = (size_t)(ks * 32 + tile) * 64 + l;
            ((uint4*)wfh)[idx] = make_uint4(hiw[0], hiw[1], hiw[2], hiw[3]);
            ((uint4*)wfl)[idx] = make_uint4(low[0], low[1], low[2], low[3]);
        }
    }
}

// ---------------------------------------------------------------------------
// A-staging (TT=32): chunk = 64 k x 64 rows (32 h | 32 ex) fp32, [row][68].
// ---------------------------------------------------------------------------
__device__ __forceinline__ void stage_ld4(const float* __restrict__ h,
                                          const float* __restrict__ ex,
                                          int tok0, int kb, int tid, float4 o[4]) {
    int row = tid >> 2, seg = tid & 3;
    const float* src = (row < 32) ? (h + (size_t)(tok0 + row) * DIM)
                                  : (ex + (size_t)(tok0 + row - 32) * DIM);
    const float* p = src + kb + seg * 16;
    o[0] = *(const float4*)(p);
    o[1] = *(const float4*)(p + 4);
    o[2] = *(const float4*)(p + 8);
    o[3] = *(const float4*)(p + 12);
}
__device__ __forceinline__ void stage_st4(float* buf, int tid, const float4 o[4]) {
    int row = tid >> 2, seg = tid & 3;
    float* d = buf + row * 68 + seg * 16;
    *(float4*)(d) = o[0];
    *(float4*)(d + 4) = o[1];
    *(float4*)(d + 8) = o[2];
    *(float4*)(d + 12) = o[3];
}

// --- B-fragment register-set load (16 coalesced 16B loads) ---
__device__ __forceinline__ void loadB(const short8* __restrict__ wph,
                                      const short8* __restrict__ wpl, int ks,
                                      short8 BH[8], short8 BL[8]) {
    const short8* bh = wph + (size_t)ks * 2048;
    const short8* bl = wpl + (size_t)ks * 2048;
#pragma unroll
    for (int t = 0; t < 8; ++t) {
        BH[t] = bh[t * 64];
        BL[t] = bl[t * 64];
    }
}

// --- one kstep: A ds_read + hi/lo convert + 48 MFMAs against a B set ---
__device__ __forceinline__ void computeStep(const float* __restrict__ ab, int abase,
                                            int ks_loc, int q8,
                                            const short8 BH[8], const short8 BL[8],
                                            f32x4 acc[2][8]) {
    const float* ar0 = ab + abase * 68 + ks_loc * 32 + q8;
    const float* ar1 = ar0 + 16 * 68;
    float4 a00 = *(const float4*)(ar0);
    float4 a01 = *(const float4*)(ar0 + 4);
    float4 a10 = *(const float4*)(ar1);
    float4 a11 = *(const float4*)(ar1 + 4);
    float av0[8] = {a00.x, a00.y, a00.z, a00.w, a01.x, a01.y, a01.z, a01.w};
    float av1[8] = {a10.x, a10.y, a10.z, a10.w, a11.x, a11.y, a11.z, a11.w};
    short8 Ah0, Al0, Ah1, Al1;
#pragma unroll
    for (int j = 0; j < 8; ++j) {
        unsigned short hb0 = f2bf_u(av0[j]);
        Ah0[j] = (short)hb0;
        Al0[j] = (short)f2bf_u(av0[j] - bf2f_u(hb0));
        unsigned short hb1 = f2bf_u(av1[j]);
        Ah1[j] = (short)hb1;
        Al1[j] = (short)f2bf_u(av1[j] - bf2f_u(hb1));
    }
#pragma unroll
    for (int t = 0; t < 8; ++t) {
        acc[0][t] = __builtin_amdgcn_mfma_f32_16x16x32_bf16(Ah0, BH[t], acc[0][t], 0, 0, 0);
        acc[1][t] = __builtin_amdgcn_mfma_f32_16x16x32_bf16(Ah1, BH[t], acc[1][t], 0, 0, 0);
        acc[0][t] = __builtin_amdgcn_mfma_f32_16x16x32_bf16(Ah0, BL[t], acc[0][t], 0, 0, 0);
        acc[1][t] = __builtin_amdgcn_mfma_f32_16x16x32_bf16(Ah1, BL[t], acc[1][t], 0, 0, 0);
        acc[0][t] = __builtin_amdgcn_mfma_f32_16x16x32_bf16(Al0, BH[t], acc[0][t], 0, 0, 0);
        acc[1][t] = __builtin_amdgcn_mfma_f32_16x16x32_bf16(Al1, BH[t], acc[1][t], 0, 0, 0);
    }
}

// ---------------------------------------------------------------------------
// Main fused kernel. 512 blocks x 256 threads, 32 tokens per block (2/CU).
// MFMA split-precision GEMM; wave w owns N-tiles 8w..8w+7 and both M-tiles.
// B-fragments SOFTWARE-PIPELINED depth-1 across ksteps (sets BH0/BL0,
// BH1/BL1): kstep i+1's 16 loads issue before kstep i's converts+MFMAs, so
// L2 latency hides under compute. Epilogue GEMMs use wave-broadcast weight
// rows (no per-lane-distinct VMEM requests).
// LDS F[15473] = 61.9 KB:
//   [0,8704)       : union { abuf[2][64*68] | a1[32][260] | cbuf[32][132] }
//   [8704,12928)   : c1[32][132]
//   [12928,14496)  : basebuf[32][49]
//   [14496,14752)  : stats[32][8]
//   [14752,15264)  : cheff_s[512]
//   [15264,15392)  : alpha_s[32][4]
//   [15392,15396)  : c4_s
//   [15396,15424)  : msw_s[28]
//   [15424,15473)  : sg_s[49] (ints)
// ---------------------------------------------------------------------------
__launch_bounds__(256, 2)
__global__ void k_main(const float* __restrict__ h, const float* __restrict__ ex,
                       const float* __restrict__ lam, const float* __restrict__ mup,
                       const float* __restrict__ bb1, const float* __restrict__ bw2,
                       const float* __restrict__ bb2, const float* __restrict__ mw2,
                       const float* __restrict__ mb2, const float* __restrict__ msw,
                       const int* __restrict__ sg, const unsigned int* __restrict__ wfh,
                       const unsigned int* __restrict__ wfl,
                       const float* __restrict__ gA, const float* __restrict__ cbias,
                       const float* __restrict__ v1w, const float* __restrict__ v2w,
                       const float* __restrict__ v3w, const float* __restrict__ cheff_t,
                       const float* __restrict__ c4, float* __restrict__ out) {
    __shared__ float F[15473];
    float* c1      = F + 8704;
    float* basebuf = F + 12928;
    float* stats   = F + 14496;
    float* cheff_s = F + 14752;
    float* alpha_s = F + 15264;
    float* c4_s    = F + 15392;
    float* msw_s   = F + 15396;
    int*   sg_s    = (int*)(F + 15424);

    const int tid = threadIdx.x;
    const int bid = blockIdx.x;
    const int tok0 = bid * TT;

    // --- small constant preloads ---
    if (tid < 49) sg_s[tid] = sg[tid];
    if (tid >= 64 && tid < 92) msw_s[tid - 64] = msw[tid - 64];
    if (tid >= 96 && tid < 100) c4_s[tid - 96] = c4[tid - 96];
    for (int i = tid; i < 512; i += 256) cheff_s[i] = cheff_t[i];

    // --- issue chunk-0 A staging loads early (latency hidden under stats) ---
    float4 p[4];
    stage_ld4(h, ex, tok0, 0, tid, p);

    // --- stats pass: 8 threads per token ---
    {
        int t = tid >> 3, r = tid & 7;
        const float* hp = h + (size_t)(tok0 + t) * DIM;
        const float* lp = lam + (size_t)(tok0 + t) * DIM;
        const float* mp = mup + (size_t)(tok0 + t) * DIM;
        float sh = 0.f, sh2 = 0.f, sll = 0.f, sll2 = 0.f, sd = 0.f;
        for (int i = 0; i < 24; i++) {
            int k0 = i * 32 + r * 4;
            float4 hv = *(const float4*)(hp + k0);
            float4 lv = *(const float4*)(lp + k0);
            float4 mv = *(const float4*)(mp + k0);
#pragma unroll
            for (int e = 0; e < 4; e++) {
                float hx = (&hv.x)[e];
                float lx = fmaxf((&lv.x)[e], 1e-6f);
                float mx = (&mv.x)[e];
                sh += hx; sh2 += hx * hx;
                float ll = logf(lx);
                sll += ll; sll2 += ll * ll;
                float dd = hx - mx; sd += dd * dd;
            }
        }
#pragma unroll
        for (int off = 1; off < 8; off <<= 1) {
            sh += __shfl_xor(sh, off);  sh2 += __shfl_xor(sh2, off);
            sll += __shfl_xor(sll, off); sll2 += __shfl_xor(sll2, off);
            sd += __shfl_xor(sd, off);
        }
        if (r == 0) {
            float m = sh * (1.f / 768.f);
            float var = sh2 * (1.f / 768.f) - m * m;
            float istd = rsqrtf(var + 1e-5f);
            float mll = sll * (1.f / 768.f);
            float vll = (sll2 - 768.f * mll * mll) * (1.f / 767.f);
            float sstd = fmaxf(sqrtf(fmaxf(vll, 0.f)), 1e-6f);
            float dmu = sqrtf(sd * (1.f / 768.f) + 1e-8f);
            float* st = stats + t * 8;
            st[0] = m; st[1] = istd; st[2] = mll; st[3] = sstd; st[4] = dmu;
        }
    }

    // --- main GEMM setup ---
    const int w = tid >> 6, l = tid & 63;
    const int lm = l & 15, lk = l >> 4;
    const int abase = ((w == 3) ? 32 : 0) + lm;  // row of M-tile 0
    const int q8 = lk * 8;

    f32x4 acc[2][8];
#pragma unroll
    for (int m = 0; m < 2; ++m)
#pragma unroll
        for (int t = 0; t < 8; ++t) acc[m][t] = (f32x4){0.f, 0.f, 0.f, 0.f};

    const short8* wph = (const short8*)wfh + (size_t)(8 * w) * 64 + l;
    const short8* wpl = (const short8*)wfl + (size_t)(8 * w) * 64 + l;

    short8 BH0[8], BL0[8], BH1[8], BL1[8];

    // --- write chunk-0 A into buffer 0; preload B set-0 before barrier ---
    stage_st4(F, tid, p);
    loadB(wph, wpl, 0, BH0, BL0);
    __syncthreads();

    int cur = 0;
    for (int c = 0; c < 12; ++c) {
        const bool more = (c + 1 < 12);
        const float* ab = F + cur * 4352;
        float* nb = F + (cur ^ 1) * 4352;
        if (more) stage_ld4(h, ex, tok0, (c + 1) * 64, tid, p);
        loadB(wph, wpl, c * 2 + 1, BH1, BL1);       // prefetch odd kstep
        computeStep(ab, abase, 0, q8, BH0, BL0, acc);
        if (more) loadB(wph, wpl, c * 2 + 2, BH0, BL0);  // prefetch next chunk's even
        computeStep(ab, abase, 1, q8, BH1, BL1, acc);
        if (more) stage_st4(nb, tid, p);
        __syncthreads();
        cur ^= 1;
    }

    // --- epilogue: lane holds token M*16 + lk*4 + r, col (8w+t)*16 + lm ---
    float* a1 = F;  // stride 260 (staging region dead)
    if (w < 2) {
#pragma unroll
        for (int t = 0; t < 8; ++t) {
            int j = (8 * w + t) * 16 + lm;
            float b = bb1[j];
#pragma unroll
            for (int m = 0; m < 2; ++m)
#pragma unroll
                for (int r = 0; r < 4; ++r)
                    a1[(m * 16 + lk * 4 + r) * 260 + j] = silu_f(acc[m][t][r] + b);
        }
    } else if (w == 2) {
#pragma unroll
        for (int t = 0; t < 8; ++t) {
            int jj = t * 16 + lm;
            float ga = gA[jj], cb = cbias[jj];
            float w1 = v1w[jj], w2 = v2w[jj], w3 = v3w[jj];
#pragma unroll
            for (int m = 0; m < 2; ++m)
#pragma unroll
                for (int r = 0; r < 4; ++r) {
                    int tok = m * 16 + lk * 4 + r;
                    const float* st = stats + tok * 8;
                    c1[tok * 132 + jj] =
                        st[1] * acc[m][t][r] - st[1] * st[0] * ga + st[2] * w1 +
                        st[3] * w2 + st[4] * w3 + cb;
                }
        }
    }
    __syncthreads();
    if (w == 3) {  // Q-side add + silu
#pragma unroll
        for (int t = 0; t < 8; ++t) {
            int jj = t * 16 + lm;
#pragma unroll
            for (int m = 0; m < 2; ++m)
#pragma unroll
                for (int r = 0; r < 4; ++r) {
                    int tok = m * 16 + lk * 4 + r;
                    float* cp = &c1[tok * 132 + jj];
                    *cp = silu_f(*cp + acc[m][t][r]);
                }
        }
    }
    __syncthreads();

    // --- GEMM1b: base = a1 @ base_w2^T + b2 (32x49, K=256). Lanes 0-31
    // share the bw2 row (broadcast); a1 LDS reads 4-way-conflict max. ---
    for (int o = tid; o < TT * 49; o += 256) {
        int t = o & 31, s = o >> 5;
        const float* ar = a1 + t * 260;
        const float* wr = bw2 + s * 256;
        float accv = bb2[s];
        for (int k = 0; k < 256; k += 4) {
            float4 av = *(const float4*)(ar + k);
            float4 wv = *(const float4*)(wr + k);
            accv += av.x * wv.x + av.y * wv.y + av.z * wv.z + av.w * wv.w;
        }
        basebuf[t * 49 + s] = accv;
    }
    __syncthreads();

    // --- GEMM2b: cmlp = c1 @ mlp_w2^T + b2 (32x128, K=128) -> cbuf.
    // t per-lane, j-group per half-wave: mw2 rows wave-broadcast. ---
    float* cbuf = F;  // stride 132
    {
        int t = tid & 31, jb = tid >> 5;  // jb in 0..7
        float accv[16];
#pragma unroll
        for (int q = 0; q < 16; q++) accv[q] = 0.f;
        const float* cr = c1 + t * 132;
        for (int k = 0; k < 128; k += 4) {
            float4 cv = *(const float4*)(cr + k);
#pragma unroll
            for (int q = 0; q < 16; q++) {
                const float* wr = mw2 + (size_t)(jb + 8 * q) * 128 + k;
                float4 wv = *(const float4*)(wr);
                accv[q] += cv.x * wv.x + cv.y * wv.y + cv.z * wv.z + cv.w * wv.w;
            }
        }
        __syncthreads();  // ensure all a1 reads (GEMM1b) done before overlay write
#pragma unroll
        for (int q = 0; q < 16; q++) {
            int j = jb + 8 * q;
            cbuf[t * 132 + j] = accv[q] + mb2[j];
        }
    }
    __syncthreads();

    // --- mode logits + softmax(4) -> alpha; write alpha to out ---
    if (tid < 128) {
        int t = tid >> 2, m = tid & 3;
        const float* cr = cbuf + t * 132;
        float e = c4_s[m];
        for (int k = 0; k < 128; k++) e += cr[k] * cheff_s[k * 4 + m];
        float mx = fmaxf(e, __shfl_xor(e, 1));
        mx = fmaxf(mx, __shfl_xor(mx, 2));
        float ev = expf(e - mx);
        float sum = ev + __shfl_xor(ev, 1);
        sum += __shfl_xor(sum, 2);
        float al = ev / sum;
        alpha_s[t * 4 + m] = al;
        out[ALPHA_OFF + (size_t)(tok0 + t) * 4 + m] = al;
    }
    __syncthreads();

    // --- K: masked stage-graph softmax over rows of 7 ---
    if (tid < TT * 7) {
        int t = tid / 7, i = tid - t * 7;
        const float* al = alpha_s + t * 4;
        float sb[7];
#pragma unroll
        for (int s = 0; s < 7; s++)
            sb[s] = al[0] * msw_s[s * 4 + 0] + al[1] * msw_s[s * 4 + 1] +
                    al[2] * msw_s[s * 4 + 2] + al[3] * msw_s[s * 4 + 3];
        const float* br = basebuf + t * 49 + i * 7;
        const int* mrow = sg_s + i * 7;
        float vals[7];
        float mx = -1e30f;
#pragma unroll
        for (int j = 0; j < 7; j++) {
            float vv = br[j] + sb[j];
            vals[j] = mrow[j] ? vv : -1e30f;
            mx = fmaxf(mx, vals[j]);
        }
        float e[7], sum = 0.f;
#pragma unroll
        for (int j = 0; j < 7; j++) {
            e[j] = mrow[j] ? expf(vals[j] - mx) : 0.f;
            sum += e[j];
        }
        float inv = 1.f / sum;
        size_t off = (size_t)(tok0 + t) * 49 + i * 7;
#pragma unroll
        for (int j = 0; j < 7; j++) out[off + j] = e[j] * inv;
    }
}

// ---------------------------------------------------------------------------
extern "C" void kernel_launch(void* const* d_in, const int* in_sizes, int n_in,
                              void* d_out, int out_size, void* d_ws, size_t ws_size,
                              hipStream_t stream) {
    const float* h    = (const float*)d_in[0];
    const float* ex   = (const float*)d_in[1];
    const float* lam  = (const float*)d_in[2];
    const float* mup  = (const float*)d_in[3];
    const float* bw1  = (const float*)d_in[4];
    const float* bb1  = (const float*)d_in[5];
    const float* bw2  = (const float*)d_in[6];
    const float* bb2  = (const float*)d_in[7];
    const float* lng  = (const float*)d_in[8];
    const float* lnb  = (const float*)d_in[9];
    const float* mw1  = (const float*)d_in[10];
    const float* mb1  = (const float*)d_in[11];
    const float* mw2  = (const float*)d_in[12];
    const float* mb2  = (const float*)d_in[13];
    const float* pe   = (const float*)d_in[14];
    const float* chw  = (const float*)d_in[15];
    const float* chb  = (const float*)d_in[16];
    const float* phw  = (const float*)d_in[17];
    const float* phb  = (const float*)d_in[18];
    const float* bil  = (const float*)d_in[19];
    const float* mob  = (const float*)d_in[20];
    const float* msw  = (const float*)d_in[21];
    const int*   sg   = (const int*)d_in[22];
    const int*   pidx = (const int*)d_in[23];
    float* out = (float*)d_out;
    float* ws = (float*)d_ws;

    unsigned int* wfh = (unsigned int*)(ws + WS_WFHI);
    unsigned int* wfl = (unsigned int*)(ws + WS_WFLO);
    float* gA    = ws + WS_GA;
    float* cbias = ws + WS_CBIAS;
    float* v1    = ws + WS_V1;
    float* v2    = ws + WS_V2;
    float* v3    = ws + WS_V3;
    float* cheff = ws + WS_CHEFF;
    float* c4    = ws + WS_C4;

    hipLaunchKernelGGL(k_prep, dim3(97), dim3(256), 0, stream, bw1, mw1, lng, mb1, lnb, pe,
                       chw, chb, phw, phb, bil, mob, pidx, wfh, wfl, gA, cbias, v1, v2, v3,
                       cheff, c4);
    hipLaunchKernelGGL(k_main, dim3(NT / TT), dim3(256), 0, stream, h, ex, lam, mup, bb1, bw2,
                       bb2, mw2, mb2, msw, sg, wfh, wfl, gA, cbias, v1, v2, v3, cheff, c4, out);
}